// Round 8
// baseline (452.391 us; speedup 1.0000x reference)
//
#include <hip/hip_runtime.h>
#include <stdint.h>
#include <math.h>

#define N_NODES  10000
#define N_EDGES  5000000
#define BATCH    2000
#define N_PAIRS  1999000   // BATCH*(BATCH-1)/2

// Output offsets (float32 elements), concatenated in reference return order
#define OUT_BN      0
#define OUT_PAIRS0  2000
#define OUT_PAIRS1  2001000
#define OUT_ES0     4000000
#define OUT_ES1     9000000
#define OUT_T       14000000
#define OUT_S       19000000
#define OUT_M       24000000

// Workspace layout (bytes)
#define WS_KEYS     0          // fill1 lives here
#define WS_SEL      80000      // 10000 x i32
#define WS_BN       120000     // 2000  x i32
#define WS_CNT      128000     // 10000 x i32 (zeroed; aliased by selbits after k_scan_all)
#define WS_FILL     168000     // 10000 x i32 (rankc first, then fill; one 80KB memset covers CNT+FILL)
#define WS_OFF      208000     // 10001 x i32
#define WS_SCRATCH  248064     // 5M x u64 keys / 5M x u32 idx

// Sort key: (i<<38) | (j<<24) | (idx<<1) | state  (14+14+23+1 = 52 bits).
// Within a row i is constant, idx unique -> order == stable (j, idx).
// Intermediate (stage/sk) write order is nondeterministic (atomic races), but
// the final rank is by full unique key -> deterministic output.

#define RPB_LOG  7
#define NB1      79            // ceil(10000 / 128) coarse buckets
#define CHUNK    4096          // edges per partition block (256 thr x 16)
#define NBITSW   313           // ceil(10000/32) sel bitmask words
#define RANK_BLKS 200          // 40 v-blocks x 5 key-chunks
#define HIST_BLKS 128          // grid-stride hist blocks

typedef unsigned long long u64;

// ---------------------------------------------------------------------------
__device__ __forceinline__ u64 score_key(int w, unsigned bits) {
  const float TINY = 1.17549435e-38f;
  float uf = __uint_as_float((bits >> 9) | 0x3f800000u) - 1.0f;
  float val = fmaxf(TINY, uf + TINY);
  float t1 = (float)log((double)val);            // inner log, rounded to f32
  float gmb = -(float)log((double)(-t1));        // outer log on f32-rounded input
  float score = (w > 0) ? ((float)log((double)w) + gmb) : (-INFINITY);
  unsigned fb = __float_as_uint(score);
  unsigned s = (fb & 0x80000000u) ? ~fb : (fb | 0x80000000u);
  unsigned d = ~s;
  return ((u64)d << 32) | (unsigned)w;
}

// JAX threefry2x32, partitionable mode: (x0,x1)=(0,v)+key; bits = out0^out1.
__device__ __forceinline__ u64 make_key(int v) {
  unsigned ks[3] = {0u, 19u, 0u ^ 19u ^ 0x1BD11BDAu};
  unsigned x0 = 0u + ks[0];
  unsigned x1 = (unsigned)v + ks[1];
  const int R0[4] = {13, 15, 26, 6};
  const int R1[4] = {17, 29, 16, 24};
#pragma unroll
  for (int g = 0; g < 5; ++g) {
    const int* R = (g & 1) ? R1 : R0;
#pragma unroll
    for (int r = 0; r < 4; ++r) {
      x0 += x1;
      x1 = (x1 << R[r]) | (x1 >> (32 - R[r]));
      x1 ^= x0;
    }
    x0 += ks[(g + 1) % 3];
    x1 += ks[(g + 2) % 3] + (unsigned)(g + 1);
  }
  return score_key(v, x0 ^ x1);
}

// Fused rank + hist. Blocks [0,200): partial rank — block (vblk,cblk) computes
// the 2048-key chunk cblk IN LDS and ranks its 256 v's against it; partial
// counts -> rankc. Blocks [200,200+HIST_BLKS): row histogram (grid-stride).
__global__ void __launch_bounds__(256) k_rankhist(
    int* __restrict__ rankc, int* __restrict__ cnt,
    const int4* __restrict__ e_i4) {
  __shared__ __align__(16) int sh4[N_NODES];   // 40000 B: lk[2048] u64 | h[10000]
  int tid = threadIdx.x;
  if ((int)blockIdx.x < RANK_BLKS) {
    u64* lk = (u64*)sh4;
    int vblk = blockIdx.x / 5, cblk = blockIdx.x % 5;
    int base = cblk * 2048;
    int lenc = min(2048, N_NODES - base);
    for (int t = tid; t < lenc; t += 256) lk[t] = make_key(base + t);
    __syncthreads();
    int v = vblk * 256 + tid;
    u64 kv = (v < N_NODES) ? make_key(v) : 0;
    int c = 0;
    for (int t = 0; t < lenc; ++t) c += (lk[t] < kv) ? 1 : 0;
    if (v < N_NODES && c) atomicAdd(&rankc[v], c);
  } else {
    int* h = sh4;
    for (int t = tid; t < N_NODES; t += 256) h[t] = 0;
    __syncthreads();
    int hb = blockIdx.x - RANK_BLKS;
    int stride = HIST_BLKS * 256;
    for (int t = hb * 256 + tid; t < N_EDGES / 4; t += stride) {
      int4 r = e_i4[t];
      atomicAdd(&h[r.x], 1);
      atomicAdd(&h[r.y], 1);
      atomicAdd(&h[r.z], 1);
      atomicAdd(&h[r.w], 1);
    }
    __syncthreads();
    for (int t = tid; t < N_NODES; t += 256) {
      int c = h[t];
      if (c) atomicAdd(&cnt[t], c);
    }
  }
}

// One block, 1024 threads; wave-shuffle scans.
// Phase 1: sel[i] = (rank < BATCH); compaction -> batch_nodes.
// Phase 2: exclusive scan cnt -> off; fill[i] = off[i]; seed coarse cursors.
//          NOTE: fill aliases rankc — all rankc reads are in phase 1 (pre-barrier).
// Phase 3: sel bitmask into selbits (aliases dead cnt).
__global__ void k_scan_all(const int* rankc, int* sel, int* bn, float* outbn,
                           const int* cnt, int* off, int* fill, int* fill1,
                           unsigned* selbits) {
  __shared__ int wsum[16];
  __shared__ unsigned lb[320];
  const int PER = 10;  // 1024*10 >= 10000
  int tid = threadIdx.x, lane = tid & 63, wid = tid >> 6;
  int base = tid * PER;
  int svv[PER];
  // ---- Phase 1 ----
  {
    int s = 0;
#pragma unroll
    for (int k = 0; k < PER; ++k) {
      int i = base + k;
      if (i < N_NODES) {
        int sv = (rankc[i] < BATCH) ? 1 : 0;
        sel[i] = sv;
        svv[k] = sv;
        s += sv;
      } else svv[k] = 0;
    }
    int inc = s;
#pragma unroll
    for (int d = 1; d < 64; d <<= 1) {
      int v = __shfl_up(inc, d, 64);
      if (lane >= d) inc += v;
    }
    if (lane == 63) wsum[wid] = inc;
    __syncthreads();
    int woff = 0;
    for (int w = 0; w < wid; ++w) woff += wsum[w];
    int run = woff + inc - s;
#pragma unroll
    for (int k = 0; k < PER; ++k) {
      int i = base + k;
      if (i < N_NODES && svv[k]) {
        bn[run] = i;
        outbn[run] = (float)i;
        ++run;
      }
    }
  }
  __syncthreads();   // wsum reuse + rankc fully read before fill writes
  // ---- Phase 2 ----
  {
    int cv[PER];
    int s = 0;
#pragma unroll
    for (int k = 0; k < PER; ++k) {
      int i = base + k;
      if (i < N_NODES) { cv[k] = cnt[i]; s += cv[k]; } else cv[k] = 0;
    }
    int inc = s;
#pragma unroll
    for (int d = 1; d < 64; d <<= 1) {
      int v = __shfl_up(inc, d, 64);
      if (lane >= d) inc += v;
    }
    if (lane == 63) wsum[wid] = inc;
    __syncthreads();
    int woff = 0;
    for (int w = 0; w < wid; ++w) woff += wsum[w];
    int run = woff + inc - s;
#pragma unroll
    for (int k = 0; k < PER; ++k) {
      int i = base + k;
      if (i < N_NODES) {
        off[i] = run;
        fill[i] = run;
        if ((i & ((1 << RPB_LOG) - 1)) == 0) fill1[i >> RPB_LOG] = run;
        run += cv[k];
      }
    }
    if (tid == 0) off[N_NODES] = N_EDGES;
  }
  // ---- Phase 3: bitmask (cnt fully consumed -> selbits may alias it) ----
  __syncthreads();
  if (tid < 320) lb[tid] = 0;
  __syncthreads();
#pragma unroll
  for (int k = 0; k < PER; ++k) {
    int i = base + k;
    if (i < N_NODES && svv[k]) atomicOr(&lb[i >> 5], 1u << (i & 31));
  }
  __syncthreads();
  if (tid < NBITSW) selbits[tid] = lb[tid];
}

// Fused: blocks [0,nblk1) = P1 coarse partition; blocks [nblk1, ...) = pairs.
// P1: partition into 79 buckets (i>>7) via LDS counting sort + coalesced drain
// (R3-proven: staged drain beats direct scatter — L2-transaction cost).
__global__ void __launch_bounds__(256) k_pairs_part1(
    const int* __restrict__ e_i, const int* __restrict__ e_j,
    const int* __restrict__ st, int* __restrict__ fill1,
    u64* __restrict__ stage, const int* __restrict__ bn,
    float* __restrict__ outp, int nblk1) {
  __shared__ u64 lkey[CHUNK];
  __shared__ int h[NB1], bstart[NB1], basec[NB1], cur[NB1];
  __shared__ int tcount_s;
  int tid = threadIdx.x;
  if ((int)blockIdx.x >= nblk1) {
    // ---- pairs ----
    int p = ((int)blockIdx.x - nblk1) * 256 + tid;
    if (p >= N_PAIRS) return;
    float tf = 2.0f * BATCH - 1.0f;
    float disc = tf * tf - 8.0f * (float)p;
    int ii = (int)((tf - sqrtf(disc)) * 0.5f);
    if (ii < 0) ii = 0;
    if (ii > BATCH - 2) ii = BATCH - 2;
    while (ii > 0 &&
           (long long)ii * (BATCH - 1) - (long long)ii * (ii - 1) / 2 > p) --ii;
    while ((long long)(ii + 1) * (BATCH - 1) - (long long)(ii + 1) * ii / 2 <= p) ++ii;
    long long S = (long long)ii * (BATCH - 1) - (long long)ii * (ii - 1) / 2;
    int jj = ii + 1 + (int)(p - S);
    outp[p] = (float)bn[ii];
    outp[N_PAIRS + p] = (float)bn[jj];
    return;
  }
  // ---- P1 ----
  int c0 = (int)blockIdx.x * CHUNK;
  int nloc = min(CHUNK, N_EDGES - c0);   // tail (2880) multiple of 4
  for (int t = tid; t < NB1; t += 256) h[t] = 0;
  __syncthreads();
  int iv[CHUNK / 256];
  const int4* e_i4 = (const int4*)(e_i + c0);
#pragma unroll
  for (int k = 0; k < CHUNK / 1024; ++k) {
    int q = tid + 256 * k;
    int ebase = 4 * q;
    if (ebase < nloc) {
      int4 r = e_i4[q];
      iv[4 * k + 0] = r.x; iv[4 * k + 1] = r.y;
      iv[4 * k + 2] = r.z; iv[4 * k + 3] = r.w;
      atomicAdd(&h[r.x >> RPB_LOG], 1);
      atomicAdd(&h[r.y >> RPB_LOG], 1);
      atomicAdd(&h[r.z >> RPB_LOG], 1);
      atomicAdd(&h[r.w >> RPB_LOG], 1);
    } else {
      iv[4 * k + 0] = iv[4 * k + 1] = iv[4 * k + 2] = iv[4 * k + 3] = -1;
    }
  }
  __syncthreads();
  // Exclusive scan of 79 bins by wave 0 (2 bins/lane + shuffle scan).
  if (tid < 64) {
    int a = h[tid];
    int b = (tid + 64 < NB1) ? h[tid + 64] : 0;
    int inc0 = a;
#pragma unroll
    for (int d = 1; d < 64; d <<= 1) {
      int v = __shfl_up(inc0, d, 64);
      if (tid >= d) inc0 += v;
    }
    int t0 = __shfl(inc0, 63, 64);
    int inc1 = b;
#pragma unroll
    for (int d = 1; d < 64; d <<= 1) {
      int v = __shfl_up(inc1, d, 64);
      if (tid >= d) inc1 += v;
    }
    int tot = t0 + __shfl(inc1, 63, 64);
    bstart[tid] = inc0 - a;
    if (tid + 64 < NB1) bstart[tid + 64] = t0 + inc1 - b;
    if (tid == 0) tcount_s = tot;
  }
  __syncthreads();
  for (int b = tid; b < NB1; b += 256) {
    basec[b] = h[b] ? atomicAdd(&fill1[b], h[b]) : 0;
    cur[b] = bstart[b];
  }
  __syncthreads();
  const int4* e_j4 = (const int4*)(e_j + c0);
  const int4* st4 = (const int4*)(st + c0);
#pragma unroll
  for (int k = 0; k < CHUNK / 1024; ++k) {
    int q = tid + 256 * k;
    int ebase = 4 * q;
    if (ebase < nloc) {
      int4 jj = e_j4[q];
      int4 ss = st4[q];
      int js[4] = {jj.x, jj.y, jj.z, jj.w};
      int s4[4] = {ss.x, ss.y, ss.z, ss.w};
#pragma unroll
      for (int c = 0; c < 4; ++c) {
        int i = iv[4 * k + c];
        unsigned e = (unsigned)(c0 + ebase + c);
        int b = i >> RPB_LOG;
        int pos = atomicAdd(&cur[b], 1);
        lkey[pos] = ((u64)(unsigned)i << 38) | ((u64)(unsigned)js[c] << 24) |
                    ((u64)e << 1) | (u64)(unsigned)s4[c];
      }
    }
  }
  __syncthreads();
  int tcount = tcount_s;
  for (int t = tid; t < tcount; t += 256) {
    u64 kv = lkey[t];
    int b = (int)(kv >> (38 + RPB_LOG));
    stage[basec[b] + (t - bstart[b])] = kv;
  }
}

// P2: fine partition bucket-grouped keys into exact row slots.
// LDS staging + coalesced drain (R3-proven); wave-shuffle scan.
__global__ void __launch_bounds__(256) k_part2(
    const u64* __restrict__ stage, int* __restrict__ fill,
    u64* __restrict__ sk) {
  __shared__ u64 lkey[CHUNK];
  __shared__ int h[256], bstart[256], baser[256], cur[256], wsum4[4];
  __shared__ int rowbase_s;
  int tid = threadIdx.x, lane = tid & 63, wid = tid >> 6;
  int c0 = (int)blockIdx.x * CHUNK;
  int nloc = min(CHUNK, N_EDGES - c0);
  h[tid] = 0;
  if (tid == 0)
    rowbase_s = ((int)(stage[c0] >> (38 + RPB_LOG))) << RPB_LOG;
  __syncthreads();
  int rowbase = rowbase_s;
  u64 kv[CHUNK / 256];
#pragma unroll
  for (int k = 0; k < CHUNK / 256; ++k) {
    int q = tid + 256 * k;
    if (q < nloc) {
      kv[k] = stage[c0 + q];
      atomicAdd(&h[(int)(kv[k] >> 38) - rowbase], 1);
    }
  }
  __syncthreads();
  int hv = h[tid];
  int inc = hv;
#pragma unroll
  for (int d = 1; d < 64; d <<= 1) {
    int v = __shfl_up(inc, d, 64);
    if (lane >= d) inc += v;
  }
  if (lane == 63) wsum4[wid] = inc;
  __syncthreads();
  int woff = 0;
  for (int w = 0; w < wid; ++w) woff += wsum4[w];
  int tcount = wsum4[0] + wsum4[1] + wsum4[2] + wsum4[3];
  int excl = woff + inc - hv;
  bstart[tid] = excl;
  cur[tid] = excl;
  baser[tid] = hv ? atomicAdd(&fill[rowbase + tid], hv) : 0;
  __syncthreads();
#pragma unroll
  for (int k = 0; k < CHUNK / 256; ++k) {
    int q = tid + 256 * k;
    if (q < nloc) {
      int lr = (int)(kv[k] >> 38) - rowbase;
      int pos = atomicAdd(&cur[lr], 1);
      lkey[pos] = kv[k];
    }
  }
  __syncthreads();
  for (int t = tid; t < tcount; t += 256) {
    u64 v = lkey[t];
    int lr = (int)(v >> 38) - rowbase;
    sk[baser[lr] + (t - bstart[lr])] = v;
  }
}

// Rowsort v10: block-per-row, ALL-PAIRS rank, 2 barriers.
// buf[t] = keys at load position (coalesced LDS writes). Rank phase: every
// lane scans buf[0..len) — all 64 lanes read the SAME address per iteration
// (broadcast, conflict-free, no atomics) and counts keys < its own (keys
// unique -> rank is a bijection onto [0,len)). buf2[rank] = key gives the
// sorted row; emit is v7's proven loop reading buf2.
__global__ void __launch_bounds__(256) k_rowsort_key(
    const u64* __restrict__ sk, const int* __restrict__ off,
    const float* __restrict__ times, const unsigned* __restrict__ selbits,
    float* __restrict__ out) {
  __shared__ u64 buf[768];
  __shared__ u64 buf2[768];
  __shared__ unsigned bits[320];
  int tid = threadIdx.x;
  int row = blockIdx.x;
  int o0 = off[row], o1 = off[row + 1];
  int len = o1 - o0;
  if (len <= 0) return;
  if (len > 768) len = 768;   // rows are 500 +- 22; 768 = +12 sigma
  int mi = (int)((selbits[row >> 5] >> (row & 31)) & 1u);  // uniform broadcast
  // Load keys (strided, coalesced); inactive slots get key 0 (never counted:
  // u64 compare b < 0 is always false).
  u64 kv[3];
  int tv[3];
#pragma unroll
  for (int k = 0; k < 3; ++k) {
    int t = tid + 256 * k;
    if (t < len) { kv[k] = sk[o0 + t]; tv[k] = t; }
    else { kv[k] = 0; tv[k] = -1; }
  }
  if (mi) {
    for (int t = tid; t < NBITSW; t += 256) bits[t] = selbits[t];
  }
#pragma unroll
  for (int k = 0; k < 3; ++k)
    if (tv[k] >= 0) buf[tv[k]] = kv[k];
  __syncthreads();   // B1: buf + bits complete
  // All-pairs rank. Uniform branch: len <= 512 -> only kv[0], kv[1] active
  // for every thread (saves 1/3 of the compares for ~70% of rows).
  int r0 = 0, r1 = 0, r2 = 0;
  if (len <= 512) {
    for (int q = 0; q < len; ++q) {
      u64 b = buf[q];
      r0 += (b < kv[0]) ? 1 : 0;
      r1 += (b < kv[1]) ? 1 : 0;
    }
  } else {
    for (int q = 0; q < len; ++q) {
      u64 b = buf[q];
      r0 += (b < kv[0]) ? 1 : 0;
      r1 += (b < kv[1]) ? 1 : 0;
      r2 += (b < kv[2]) ? 1 : 0;
    }
  }
  if (tv[0] >= 0) buf2[r0] = kv[0];
  if (tv[1] >= 0) buf2[r1] = kv[1];
  if (tv[2] >= 0) buf2[r2] = kv[2];
  __syncthreads();   // B2: buf2 sorted
  // Coalesced emit (v7-proven); fast path for unselected rows.
  float frow = (float)row;
  if (mi) {
    for (int t = tid; t < len; t += 256) {
      u64 k = buf2[t];
      int j = (int)((k >> 24) & 0x3FFFull);
      int idx = (int)((k >> 1) & 0x7FFFFFull);
      int st = (int)(k & 1ull);
      int p = o0 + t;
      out[OUT_ES0 + p] = frow;
      out[OUT_ES1 + p] = (float)j;
      bool m = (bits[j >> 5] >> (j & 31)) & 1u;
      out[OUT_T + p] = m ? times[idx] : 0.0f;
      out[OUT_S + p] = m ? (float)st : 0.0f;
      out[OUT_M + p] = m ? 1.0f : 0.0f;
    }
  } else {
    for (int t = tid; t < len; t += 256) {
      u64 k = buf2[t];
      int j = (int)((k >> 24) & 0x3FFFull);
      int p = o0 + t;
      out[OUT_ES0 + p] = frow;
      out[OUT_ES1 + p] = (float)j;
      out[OUT_T + p] = 0.0f;
      out[OUT_S + p] = 0.0f;
      out[OUT_M + p] = 0.0f;
    }
  }
}

// ---- Fallback path (ws too small for u64 keys): R4-style 4B idx scatter ----
__global__ void __launch_bounds__(256) k_scatter_idx(
    const int4* __restrict__ e_i4, int* __restrict__ fill,
    unsigned* __restrict__ sk) {
  int t = blockIdx.x * blockDim.x + threadIdx.x;
  if (t >= N_EDGES / 4) return;
  int4 r = e_i4[t];
  unsigned e = 4u * (unsigned)t;
  int c0 = atomicAdd(&fill[r.x], 1);
  int c1 = atomicAdd(&fill[r.y], 1);
  int c2 = atomicAdd(&fill[r.z], 1);
  int c3 = atomicAdd(&fill[r.w], 1);
  sk[c0] = e;
  sk[c1] = e + 1;
  sk[c2] = e + 2;
  sk[c3] = e + 3;
}

__global__ void __launch_bounds__(256) k_rowsort_idx(
    const unsigned* __restrict__ sk, const int* __restrict__ e_j_arr,
    const int* __restrict__ off, const float* __restrict__ times,
    const int* __restrict__ states, const int* __restrict__ sel,
    float* __restrict__ out) {
  __shared__ u64 key[2048];
  int row = blockIdx.x;
  int o0 = off[row], o1 = off[row + 1];
  int len = o1 - o0;
  if (len <= 0) return;
  if (len > 2048) len = 2048;
  int M = 2;
  while (M < len) M <<= 1;
  for (int t = threadIdx.x; t < M; t += blockDim.x) {
    if (t < len) {
      unsigned e = sk[o0 + t];
      key[t] = ((u64)(unsigned)e_j_arr[e] << 32) | e;
    } else {
      key[t] = 0xFFFFFFFFFFFFFFFFull;
    }
  }
  __syncthreads();
  for (int k = 2; k <= M; k <<= 1) {
    for (int j = k >> 1; j > 0; j >>= 1) {
      for (int t = threadIdx.x; t < M; t += blockDim.x) {
        int ixj = t ^ j;
        if (ixj > t) {
          u64 a = key[t], b = key[ixj];
          bool up = ((t & k) == 0);
          if (up ? (a > b) : (a < b)) {
            key[t] = b;
            key[ixj] = a;
          }
        }
      }
      __syncthreads();
    }
  }
  int mi = sel[row];
  float frow = (float)row;
  for (int t = threadIdx.x; t < len; t += blockDim.x) {
    u64 k = key[t];
    int j = (int)(k >> 32);
    int idx = (int)(k & 0xFFFFFFFFull);
    int p = o0 + t;
    out[OUT_ES0 + p] = frow;
    out[OUT_ES1 + p] = (float)j;
    bool m = (mi != 0) && (sel[j] != 0);
    float tm = 0.0f, sv = 0.0f;
    if (m) {
      tm = times[idx];
      sv = (float)states[idx];
    }
    out[OUT_T + p] = tm;
    out[OUT_S + p] = sv;
    out[OUT_M + p] = m ? 1.0f : 0.0f;
  }
}

extern "C" void kernel_launch(void* const* d_in, const int* in_sizes, int n_in,
                              void* d_out, int out_size, void* d_ws, size_t ws_size,
                              hipStream_t stream) {
  const int* edges = (const int*)d_in[0];       // (2, E): [0..E)=i, [E..2E)=j
  const float* times = (const float*)d_in[1];
  const int* states = (const int*)d_in[2];
  const int* e_i = edges;
  const int* e_j = edges + N_EDGES;
  float* out = (float*)d_out;
  char* ws = (char*)d_ws;

  int* fill1 = (int*)(ws + WS_KEYS);
  int* sel = (int*)(ws + WS_SEL);
  int* bn = (int*)(ws + WS_BN);
  int* cnt = (int*)(ws + WS_CNT);
  unsigned* selbits = (unsigned*)(ws + WS_CNT); // aliases cnt (dead after scan)
  int* fill = (int*)(ws + WS_FILL);
  int* rankc = (int*)(ws + WS_FILL);            // rankc aliases fill (phase-ordered)
  int* off = (int*)(ws + WS_OFF);
  u64* sk64 = (u64*)(ws + WS_SCRATCH);
  unsigned* sk32 = (unsigned*)(ws + WS_SCRATCH);
  // Staging buffer for P1 output: the es0/es1 output region (exactly 40 MB),
  // fully consumed by P2 before k_rowsort_key overwrites it.
  u64* stage = (u64*)(out + OUT_ES0);
  int use64 = (ws_size >= (size_t)WS_SCRATCH + 8ull * N_EDGES) ? 1 : 0;

  hipMemsetAsync(ws + WS_CNT, 0, 80000, stream);  // cnt + rankc (contiguous)

  int npair_b = (N_PAIRS + 255) / 256;
  k_rankhist<<<RANK_BLKS + HIST_BLKS, 256, 0, stream>>>(rankc, cnt,
                                                        (const int4*)e_i);
  k_scan_all<<<1, 1024, 0, stream>>>(rankc, sel, bn, out + OUT_BN, cnt, off,
                                     fill, fill1, selbits);
  if (use64) {
    int nblk1 = (N_EDGES + CHUNK - 1) / CHUNK;
    k_pairs_part1<<<nblk1 + npair_b, 256, 0, stream>>>(
        e_i, e_j, states, fill1, stage, bn, out + OUT_PAIRS0, nblk1);
    k_part2<<<nblk1, 256, 0, stream>>>(stage, fill, sk64);
    k_rowsort_key<<<N_NODES, 256, 0, stream>>>(sk64, off, times, selbits, out);
  } else {
    k_pairs_part1<<<npair_b, 256, 0, stream>>>(
        e_i, e_j, states, fill1, stage, bn, out + OUT_PAIRS0, 0);
    k_scatter_idx<<<(N_EDGES / 4 + 255) / 256, 256, 0, stream>>>(
        (const int4*)e_i, fill, sk32);
    k_rowsort_idx<<<N_NODES, 256, 0, stream>>>(sk32, e_j, off, times, states,
                                               sel, out);
  }
}

// Round 9
// 419.307 us; speedup vs baseline: 1.0789x; 1.0789x over previous
//
#include <hip/hip_runtime.h>
#include <stdint.h>
#include <math.h>

#define N_NODES  10000
#define N_EDGES  5000000
#define BATCH    2000
#define N_PAIRS  1999000   // BATCH*(BATCH-1)/2

// Output offsets (float32 elements), concatenated in reference return order
#define OUT_BN      0
#define OUT_PAIRS0  2000
#define OUT_PAIRS1  2001000
#define OUT_ES0     4000000
#define OUT_ES1     9000000
#define OUT_T       14000000
#define OUT_S       19000000
#define OUT_M       24000000

// Workspace layout (bytes)
#define WS_KEYS     0          // fill1 lives here
#define WS_SEL      80000      // 10000 x i32
#define WS_BN       120000     // 2000  x i32
#define WS_CNT      128000     // 10000 x i32 (zeroed; aliased by selbits after k_scan_all)
#define WS_FILL     168000     // 10000 x i32 (rankc first, then fill; one 80KB memset covers CNT+FILL)
#define WS_OFF      208000     // 10001 x i32
#define WS_SCRATCH  248064     // 5M x u64 keys / 5M x u32 idx

// Sort key: (i<<38) | (j<<24) | (idx<<1) | state  (14+14+23+1 = 52 bits).
// Within a row i is constant, idx unique -> order == stable (j, idx).
// Intermediate (stage/sk) write order is nondeterministic (atomic races), but
// the final rank is by full unique key -> deterministic output.

#define RPB_LOG  7
#define NB1      79            // ceil(10000 / 128) coarse buckets
#define CHUNK    4096          // edges per partition block (256 thr x 16)
#define NBIN     192           // row-sort bins (adaptive shift keeps used bins <= 160)
#define NBITSW   313           // ceil(10000/32) sel bitmask words
#define RANK_BLKS 200          // 40 v-blocks x 5 key-chunks
#define HIST_BLKS 128          // grid-stride hist blocks
#define RPB      4             // rowsort rows per block (serial)

typedef unsigned long long u64;

// ---------------------------------------------------------------------------
__device__ __forceinline__ u64 score_key(int w, unsigned bits) {
  const float TINY = 1.17549435e-38f;
  float uf = __uint_as_float((bits >> 9) | 0x3f800000u) - 1.0f;
  float val = fmaxf(TINY, uf + TINY);
  float t1 = (float)log((double)val);            // inner log, rounded to f32
  float gmb = -(float)log((double)(-t1));        // outer log on f32-rounded input
  float score = (w > 0) ? ((float)log((double)w) + gmb) : (-INFINITY);
  unsigned fb = __float_as_uint(score);
  unsigned s = (fb & 0x80000000u) ? ~fb : (fb | 0x80000000u);
  unsigned d = ~s;
  return ((u64)d << 32) | (unsigned)w;
}

// JAX threefry2x32, partitionable mode: (x0,x1)=(0,v)+key; bits = out0^out1.
__device__ __forceinline__ u64 make_key(int v) {
  unsigned ks[3] = {0u, 19u, 0u ^ 19u ^ 0x1BD11BDAu};
  unsigned x0 = 0u + ks[0];
  unsigned x1 = (unsigned)v + ks[1];
  const int R0[4] = {13, 15, 26, 6};
  const int R1[4] = {17, 29, 16, 24};
#pragma unroll
  for (int g = 0; g < 5; ++g) {
    const int* R = (g & 1) ? R1 : R0;
#pragma unroll
    for (int r = 0; r < 4; ++r) {
      x0 += x1;
      x1 = (x1 << R[r]) | (x1 >> (32 - R[r]));
      x1 ^= x0;
    }
    x0 += ks[(g + 1) % 3];
    x1 += ks[(g + 2) % 3] + (unsigned)(g + 1);
  }
  return score_key(v, x0 ^ x1);
}

// Fused rank + hist. Blocks [0,200): partial rank — block (vblk,cblk) computes
// the 2048-key chunk cblk IN LDS and ranks its 256 v's against it; partial
// counts -> rankc. Blocks [200,200+HIST_BLKS): row histogram (grid-stride).
__global__ void __launch_bounds__(256) k_rankhist(
    int* __restrict__ rankc, int* __restrict__ cnt,
    const int4* __restrict__ e_i4) {
  __shared__ __align__(16) int sh4[N_NODES];   // 40000 B: lk[2048] u64 | h[10000]
  int tid = threadIdx.x;
  if ((int)blockIdx.x < RANK_BLKS) {
    u64* lk = (u64*)sh4;
    int vblk = blockIdx.x / 5, cblk = blockIdx.x % 5;
    int base = cblk * 2048;
    int lenc = min(2048, N_NODES - base);
    for (int t = tid; t < lenc; t += 256) lk[t] = make_key(base + t);
    __syncthreads();
    int v = vblk * 256 + tid;
    u64 kv = (v < N_NODES) ? make_key(v) : 0;
    int c = 0;
    for (int t = 0; t < lenc; ++t) c += (lk[t] < kv) ? 1 : 0;
    if (v < N_NODES && c) atomicAdd(&rankc[v], c);
  } else {
    int* h = sh4;
    for (int t = tid; t < N_NODES; t += 256) h[t] = 0;
    __syncthreads();
    int hb = blockIdx.x - RANK_BLKS;
    int stride = HIST_BLKS * 256;
    for (int t = hb * 256 + tid; t < N_EDGES / 4; t += stride) {
      int4 r = e_i4[t];
      atomicAdd(&h[r.x], 1);
      atomicAdd(&h[r.y], 1);
      atomicAdd(&h[r.z], 1);
      atomicAdd(&h[r.w], 1);
    }
    __syncthreads();
    for (int t = tid; t < N_NODES; t += 256) {
      int c = h[t];
      if (c) atomicAdd(&cnt[t], c);
    }
  }
}

// One block, 1024 threads; wave-shuffle scans.
// Phase 1: sel[i] = (rank < BATCH); compaction -> batch_nodes.
// Phase 2: exclusive scan cnt -> off; fill[i] = off[i]; seed coarse cursors.
//          NOTE: fill aliases rankc — all rankc reads are in phase 1 (pre-barrier).
// Phase 3: sel bitmask into selbits (aliases dead cnt).
__global__ void k_scan_all(const int* rankc, int* sel, int* bn, float* outbn,
                           const int* cnt, int* off, int* fill, int* fill1,
                           unsigned* selbits) {
  __shared__ int wsum[16];
  __shared__ unsigned lb[320];
  const int PER = 10;  // 1024*10 >= 10000
  int tid = threadIdx.x, lane = tid & 63, wid = tid >> 6;
  int base = tid * PER;
  int svv[PER];
  // ---- Phase 1 ----
  {
    int s = 0;
#pragma unroll
    for (int k = 0; k < PER; ++k) {
      int i = base + k;
      if (i < N_NODES) {
        int sv = (rankc[i] < BATCH) ? 1 : 0;
        sel[i] = sv;
        svv[k] = sv;
        s += sv;
      } else svv[k] = 0;
    }
    int inc = s;
#pragma unroll
    for (int d = 1; d < 64; d <<= 1) {
      int v = __shfl_up(inc, d, 64);
      if (lane >= d) inc += v;
    }
    if (lane == 63) wsum[wid] = inc;
    __syncthreads();
    int woff = 0;
    for (int w = 0; w < wid; ++w) woff += wsum[w];
    int run = woff + inc - s;
#pragma unroll
    for (int k = 0; k < PER; ++k) {
      int i = base + k;
      if (i < N_NODES && svv[k]) {
        bn[run] = i;
        outbn[run] = (float)i;
        ++run;
      }
    }
  }
  __syncthreads();   // wsum reuse + rankc fully read before fill writes
  // ---- Phase 2 ----
  {
    int cv[PER];
    int s = 0;
#pragma unroll
    for (int k = 0; k < PER; ++k) {
      int i = base + k;
      if (i < N_NODES) { cv[k] = cnt[i]; s += cv[k]; } else cv[k] = 0;
    }
    int inc = s;
#pragma unroll
    for (int d = 1; d < 64; d <<= 1) {
      int v = __shfl_up(inc, d, 64);
      if (lane >= d) inc += v;
    }
    if (lane == 63) wsum[wid] = inc;
    __syncthreads();
    int woff = 0;
    for (int w = 0; w < wid; ++w) woff += wsum[w];
    int run = woff + inc - s;
#pragma unroll
    for (int k = 0; k < PER; ++k) {
      int i = base + k;
      if (i < N_NODES) {
        off[i] = run;
        fill[i] = run;
        if ((i & ((1 << RPB_LOG) - 1)) == 0) fill1[i >> RPB_LOG] = run;
        run += cv[k];
      }
    }
    if (tid == 0) off[N_NODES] = N_EDGES;
  }
  // ---- Phase 3: bitmask (cnt fully consumed -> selbits may alias it) ----
  __syncthreads();
  if (tid < 320) lb[tid] = 0;
  __syncthreads();
#pragma unroll
  for (int k = 0; k < PER; ++k) {
    int i = base + k;
    if (i < N_NODES && svv[k]) atomicOr(&lb[i >> 5], 1u << (i & 31));
  }
  __syncthreads();
  if (tid < NBITSW) selbits[tid] = lb[tid];
}

// Fused: blocks [0,nblk1) = P1 coarse partition; blocks [nblk1, ...) = pairs.
// P1: partition into 79 buckets (i>>7) via LDS counting sort + coalesced drain
// (R3-proven: staged drain beats direct scatter — L2-transaction cost).
__global__ void __launch_bounds__(256) k_pairs_part1(
    const int* __restrict__ e_i, const int* __restrict__ e_j,
    const int* __restrict__ st, int* __restrict__ fill1,
    u64* __restrict__ stage, const int* __restrict__ bn,
    float* __restrict__ outp, int nblk1) {
  __shared__ u64 lkey[CHUNK];
  __shared__ int h[NB1], bstart[NB1], basec[NB1], cur[NB1];
  __shared__ int tcount_s;
  int tid = threadIdx.x;
  if ((int)blockIdx.x >= nblk1) {
    // ---- pairs ----
    int p = ((int)blockIdx.x - nblk1) * 256 + tid;
    if (p >= N_PAIRS) return;
    float tf = 2.0f * BATCH - 1.0f;
    float disc = tf * tf - 8.0f * (float)p;
    int ii = (int)((tf - sqrtf(disc)) * 0.5f);
    if (ii < 0) ii = 0;
    if (ii > BATCH - 2) ii = BATCH - 2;
    while (ii > 0 &&
           (long long)ii * (BATCH - 1) - (long long)ii * (ii - 1) / 2 > p) --ii;
    while ((long long)(ii + 1) * (BATCH - 1) - (long long)(ii + 1) * ii / 2 <= p) ++ii;
    long long S = (long long)ii * (BATCH - 1) - (long long)ii * (ii - 1) / 2;
    int jj = ii + 1 + (int)(p - S);
    outp[p] = (float)bn[ii];
    outp[N_PAIRS + p] = (float)bn[jj];
    return;
  }
  // ---- P1 ----
  int c0 = (int)blockIdx.x * CHUNK;
  int nloc = min(CHUNK, N_EDGES - c0);   // tail (2880) multiple of 4
  for (int t = tid; t < NB1; t += 256) h[t] = 0;
  __syncthreads();
  int iv[CHUNK / 256];
  const int4* e_i4 = (const int4*)(e_i + c0);
#pragma unroll
  for (int k = 0; k < CHUNK / 1024; ++k) {
    int q = tid + 256 * k;
    int ebase = 4 * q;
    if (ebase < nloc) {
      int4 r = e_i4[q];
      iv[4 * k + 0] = r.x; iv[4 * k + 1] = r.y;
      iv[4 * k + 2] = r.z; iv[4 * k + 3] = r.w;
      atomicAdd(&h[r.x >> RPB_LOG], 1);
      atomicAdd(&h[r.y >> RPB_LOG], 1);
      atomicAdd(&h[r.z >> RPB_LOG], 1);
      atomicAdd(&h[r.w >> RPB_LOG], 1);
    } else {
      iv[4 * k + 0] = iv[4 * k + 1] = iv[4 * k + 2] = iv[4 * k + 3] = -1;
    }
  }
  __syncthreads();
  // Exclusive scan of 79 bins by wave 0 (2 bins/lane + shuffle scan).
  if (tid < 64) {
    int a = h[tid];
    int b = (tid + 64 < NB1) ? h[tid + 64] : 0;
    int inc0 = a;
#pragma unroll
    for (int d = 1; d < 64; d <<= 1) {
      int v = __shfl_up(inc0, d, 64);
      if (tid >= d) inc0 += v;
    }
    int t0 = __shfl(inc0, 63, 64);
    int inc1 = b;
#pragma unroll
    for (int d = 1; d < 64; d <<= 1) {
      int v = __shfl_up(inc1, d, 64);
      if (tid >= d) inc1 += v;
    }
    int tot = t0 + __shfl(inc1, 63, 64);
    bstart[tid] = inc0 - a;
    if (tid + 64 < NB1) bstart[tid + 64] = t0 + inc1 - b;
    if (tid == 0) tcount_s = tot;
  }
  __syncthreads();
  for (int b = tid; b < NB1; b += 256) {
    basec[b] = h[b] ? atomicAdd(&fill1[b], h[b]) : 0;
    cur[b] = bstart[b];
  }
  __syncthreads();
  const int4* e_j4 = (const int4*)(e_j + c0);
  const int4* st4 = (const int4*)(st + c0);
#pragma unroll
  for (int k = 0; k < CHUNK / 1024; ++k) {
    int q = tid + 256 * k;
    int ebase = 4 * q;
    if (ebase < nloc) {
      int4 jj = e_j4[q];
      int4 ss = st4[q];
      int js[4] = {jj.x, jj.y, jj.z, jj.w};
      int s4[4] = {ss.x, ss.y, ss.z, ss.w};
#pragma unroll
      for (int c = 0; c < 4; ++c) {
        int i = iv[4 * k + c];
        unsigned e = (unsigned)(c0 + ebase + c);
        int b = i >> RPB_LOG;
        int pos = atomicAdd(&cur[b], 1);
        lkey[pos] = ((u64)(unsigned)i << 38) | ((u64)(unsigned)js[c] << 24) |
                    ((u64)e << 1) | (u64)(unsigned)s4[c];
      }
    }
  }
  __syncthreads();
  int tcount = tcount_s;
  for (int t = tid; t < tcount; t += 256) {
    u64 kv = lkey[t];
    int b = (int)(kv >> (38 + RPB_LOG));
    stage[basec[b] + (t - bstart[b])] = kv;
  }
}

// P2: fine partition bucket-grouped keys into exact row slots.
// LDS staging + coalesced drain (R3-proven); wave-shuffle scan.
__global__ void __launch_bounds__(256) k_part2(
    const u64* __restrict__ stage, int* __restrict__ fill,
    u64* __restrict__ sk) {
  __shared__ u64 lkey[CHUNK];
  __shared__ int h[256], bstart[256], baser[256], cur[256], wsum4[4];
  __shared__ int rowbase_s;
  int tid = threadIdx.x, lane = tid & 63, wid = tid >> 6;
  int c0 = (int)blockIdx.x * CHUNK;
  int nloc = min(CHUNK, N_EDGES - c0);
  h[tid] = 0;
  if (tid == 0)
    rowbase_s = ((int)(stage[c0] >> (38 + RPB_LOG))) << RPB_LOG;
  __syncthreads();
  int rowbase = rowbase_s;
  u64 kv[CHUNK / 256];
#pragma unroll
  for (int k = 0; k < CHUNK / 256; ++k) {
    int q = tid + 256 * k;
    if (q < nloc) {
      kv[k] = stage[c0 + q];
      atomicAdd(&h[(int)(kv[k] >> 38) - rowbase], 1);
    }
  }
  __syncthreads();
  int hv = h[tid];
  int inc = hv;
#pragma unroll
  for (int d = 1; d < 64; d <<= 1) {
    int v = __shfl_up(inc, d, 64);
    if (lane >= d) inc += v;
  }
  if (lane == 63) wsum4[wid] = inc;
  __syncthreads();
  int woff = 0;
  for (int w = 0; w < wid; ++w) woff += wsum4[w];
  int tcount = wsum4[0] + wsum4[1] + wsum4[2] + wsum4[3];
  int excl = woff + inc - hv;
  bstart[tid] = excl;
  cur[tid] = excl;
  baser[tid] = hv ? atomicAdd(&fill[rowbase + tid], hv) : 0;
  __syncthreads();
#pragma unroll
  for (int k = 0; k < CHUNK / 256; ++k) {
    int q = tid + 256 * k;
    if (q < nloc) {
      int lr = (int)(kv[k] >> 38) - rowbase;
      int pos = atomicAdd(&cur[lr], 1);
      lkey[pos] = kv[k];
    }
  }
  __syncthreads();
  for (int t = tid; t < tcount; t += 256) {
    u64 v = lkey[t];
    int lr = (int)(v >> 38) - rowbase;
    sk[baser[lr] + (t - bstart[lr])] = v;
  }
}

// Rowsort v11: v7's proven pipeline, 4 rows serially per block (grid 2500).
// Amortized per block: launch, off[] (one LDS preload), bits (one load).
// Keys for row r+1 are issued at the top of row r -> HBM latency hides under
// the full 6-phase chain of row r instead of one short phase.
__global__ void __launch_bounds__(256) k_rowsort_key(
    const u64* __restrict__ sk, const int* __restrict__ off,
    const float* __restrict__ times, const unsigned* __restrict__ selbits,
    float* __restrict__ out) {
  __shared__ u64 buf[768];
  __shared__ int hist[NBIN], cur[NBIN];
  __shared__ unsigned bits[320];
  __shared__ int offs[RPB + 1];
  int tid = threadIdx.x;
  int base_row = (int)blockIdx.x * RPB;          // grid 2500 -> rows < 10000
  if (tid < RPB + 1) offs[tid] = off[base_row + tid];
  for (int t = tid; t < NBITSW; t += 256) bits[t] = selbits[t];
  // Prologue: issue row-0 key loads (uniform off reads; L2-hot).
  u64 pv[3];
  {
    int p0 = off[base_row], p1 = off[base_row + 1];
    int plen = p1 - p0;
    if (plen > 768) plen = 768;
#pragma unroll
    for (int k = 0; k < 3; ++k) {
      int t = tid + 256 * k;
      pv[k] = (t < plen) ? sk[p0 + t] : 0;
    }
  }
  __syncthreads();   // F1: offs + bits visible
  for (int r = 0; r < RPB; ++r) {
    int row = base_row + r;
    int o0 = offs[r], o1 = offs[r + 1];
    int len = o1 - o0;
    if (len > 768) len = 768;   // rows are 500 +- 22; 768 = +12 sigma
    // Consume prefetch (s_waitcnt lands here), then immediately issue next
    // row's loads so they fly across this row's whole phase chain.
    u64 kv[3];
#pragma unroll
    for (int k = 0; k < 3; ++k) kv[k] = pv[k];
    if (r + 1 < RPB) {
      int n0 = offs[r + 1];
      int nlen = offs[r + 2] - n0;
      if (nlen > 768) nlen = 768;
#pragma unroll
      for (int k = 0; k < 3; ++k) {
        int t = tid + 256 * k;
        pv[k] = (t < nlen) ? sk[n0 + t] : 0;
      }
    }
    if (len <= 0) continue;     // uniform (row 9999 only)
    int span = N_NODES - 1 - row;
    int s = 0;
    while ((span >> s) >= 160) ++s;   // bins used <= 160
    int mi = (int)((bits[row >> 5] >> (row & 31)) & 1u);  // uniform
    for (int t = tid; t < NBIN; t += 256) hist[t] = 0;
    __syncthreads();   // B1: hist zeroed (prev row's phases all done)
    // Histogram from registers.
    int dv[3], rv[3];
    int jbase = row + 1;
#pragma unroll
    for (int k = 0; k < 3; ++k) {
      int t = tid + 256 * k;
      if (t < len) {
        int j = (int)((kv[k] >> 24) & 0x3FFFull);
        int d = (j - jbase) >> s;
        dv[k] = d;
        atomicAdd(&hist[d], 1);
      } else {
        dv[k] = -1;
      }
    }
    __syncthreads();   // B2
    // Exclusive scan of NBIN bins by wave 0 (3 bins/lane + shuffle scan).
    if (tid < 64) {
      int b0 = tid * 3;
      int c0 = hist[b0], c1 = hist[b0 + 1], c2 = hist[b0 + 2];
      int sum = c0 + c1 + c2;
      int inc = sum;
#pragma unroll
      for (int d = 1; d < 64; d <<= 1) {
        int v = __shfl_up(inc, d, 64);
        if (tid >= d) inc += v;
      }
      int excl = inc - sum;
      hist[b0] = excl;
      hist[b0 + 1] = excl + c0;
      hist[b0 + 2] = excl + c0 + c1;
      cur[b0] = excl;
      cur[b0 + 1] = excl + c0;
      cur[b0 + 2] = excl + c0 + c1;
    }
    __syncthreads();   // B3
    // Scatter into buckets (order within bucket arbitrary).
#pragma unroll
    for (int k = 0; k < 3; ++k) {
      if (dv[k] >= 0) {
        int pos = atomicAdd(&cur[dv[k]], 1);
        buf[pos] = kv[k];
      }
    }
    __syncthreads();   // B4
    // Rank within bucket by full key (unique); bounds [hist[d], cur[d]).
#pragma unroll
    for (int k = 0; k < 3; ++k) {
      if (dv[k] >= 0) {
        u64 me = kv[k];
        int s0 = hist[dv[k]];
        int s1 = cur[dv[k]];
        int rr = 0;
        for (int q = s0; q < s1; ++q) rr += (buf[q] < me) ? 1 : 0;
        rv[k] = s0 + rr;
      }
    }
    __syncthreads();   // B5: rank reads done before in-place writeback
#pragma unroll
    for (int k = 0; k < 3; ++k)
      if (dv[k] >= 0) buf[rv[k]] = kv[k];
    __syncthreads();   // B6
    // Coalesced emit; fast path for unselected rows.
    float frow = (float)row;
    if (mi) {
      for (int t = tid; t < len; t += 256) {
        u64 k = buf[t];
        int j = (int)((k >> 24) & 0x3FFFull);
        int idx = (int)((k >> 1) & 0x7FFFFFull);
        int st = (int)(k & 1ull);
        int p = o0 + t;
        out[OUT_ES0 + p] = frow;
        out[OUT_ES1 + p] = (float)j;
        bool m = (bits[j >> 5] >> (j & 31)) & 1u;
        out[OUT_T + p] = m ? times[idx] : 0.0f;
        out[OUT_S + p] = m ? (float)st : 0.0f;
        out[OUT_M + p] = m ? 1.0f : 0.0f;
      }
    } else {
      for (int t = tid; t < len; t += 256) {
        u64 k = buf[t];
        int j = (int)((k >> 24) & 0x3FFFull);
        int p = o0 + t;
        out[OUT_ES0 + p] = frow;
        out[OUT_ES1 + p] = (float)j;
        out[OUT_T + p] = 0.0f;
        out[OUT_S + p] = 0.0f;
        out[OUT_M + p] = 0.0f;
      }
    }
    __syncthreads();   // B7: buf free before next row's scatter
  }
}

// ---- Fallback path (ws too small for u64 keys): R4-style 4B idx scatter ----
__global__ void __launch_bounds__(256) k_scatter_idx(
    const int4* __restrict__ e_i4, int* __restrict__ fill,
    unsigned* __restrict__ sk) {
  int t = blockIdx.x * blockDim.x + threadIdx.x;
  if (t >= N_EDGES / 4) return;
  int4 r = e_i4[t];
  unsigned e = 4u * (unsigned)t;
  int c0 = atomicAdd(&fill[r.x], 1);
  int c1 = atomicAdd(&fill[r.y], 1);
  int c2 = atomicAdd(&fill[r.z], 1);
  int c3 = atomicAdd(&fill[r.w], 1);
  sk[c0] = e;
  sk[c1] = e + 1;
  sk[c2] = e + 2;
  sk[c3] = e + 3;
}

__global__ void __launch_bounds__(256) k_rowsort_idx(
    const unsigned* __restrict__ sk, const int* __restrict__ e_j_arr,
    const int* __restrict__ off, const float* __restrict__ times,
    const int* __restrict__ states, const int* __restrict__ sel,
    float* __restrict__ out) {
  __shared__ u64 key[2048];
  int row = blockIdx.x;
  int o0 = off[row], o1 = off[row + 1];
  int len = o1 - o0;
  if (len <= 0) return;
  if (len > 2048) len = 2048;
  int M = 2;
  while (M < len) M <<= 1;
  for (int t = threadIdx.x; t < M; t += blockDim.x) {
    if (t < len) {
      unsigned e = sk[o0 + t];
      key[t] = ((u64)(unsigned)e_j_arr[e] << 32) | e;
    } else {
      key[t] = 0xFFFFFFFFFFFFFFFFull;
    }
  }
  __syncthreads();
  for (int k = 2; k <= M; k <<= 1) {
    for (int j = k >> 1; j > 0; j >>= 1) {
      for (int t = threadIdx.x; t < M; t += blockDim.x) {
        int ixj = t ^ j;
        if (ixj > t) {
          u64 a = key[t], b = key[ixj];
          bool up = ((t & k) == 0);
          if (up ? (a > b) : (a < b)) {
            key[t] = b;
            key[ixj] = a;
          }
        }
      }
      __syncthreads();
    }
  }
  int mi = sel[row];
  float frow = (float)row;
  for (int t = threadIdx.x; t < len; t += blockDim.x) {
    u64 k = key[t];
    int j = (int)(k >> 32);
    int idx = (int)(k & 0xFFFFFFFFull);
    int p = o0 + t;
    out[OUT_ES0 + p] = frow;
    out[OUT_ES1 + p] = (float)j;
    bool m = (mi != 0) && (sel[j] != 0);
    float tm = 0.0f, sv = 0.0f;
    if (m) {
      tm = times[idx];
      sv = (float)states[idx];
    }
    out[OUT_T + p] = tm;
    out[OUT_S + p] = sv;
    out[OUT_M + p] = m ? 1.0f : 0.0f;
  }
}

extern "C" void kernel_launch(void* const* d_in, const int* in_sizes, int n_in,
                              void* d_out, int out_size, void* d_ws, size_t ws_size,
                              hipStream_t stream) {
  const int* edges = (const int*)d_in[0];       // (2, E): [0..E)=i, [E..2E)=j
  const float* times = (const float*)d_in[1];
  const int* states = (const int*)d_in[2];
  const int* e_i = edges;
  const int* e_j = edges + N_EDGES;
  float* out = (float*)d_out;
  char* ws = (char*)d_ws;

  int* fill1 = (int*)(ws + WS_KEYS);
  int* sel = (int*)(ws + WS_SEL);
  int* bn = (int*)(ws + WS_BN);
  int* cnt = (int*)(ws + WS_CNT);
  unsigned* selbits = (unsigned*)(ws + WS_CNT); // aliases cnt (dead after scan)
  int* fill = (int*)(ws + WS_FILL);
  int* rankc = (int*)(ws + WS_FILL);            // rankc aliases fill (phase-ordered)
  int* off = (int*)(ws + WS_OFF);
  u64* sk64 = (u64*)(ws + WS_SCRATCH);
  unsigned* sk32 = (unsigned*)(ws + WS_SCRATCH);
  // Staging buffer for P1 output: the es0/es1 output region (exactly 40 MB),
  // fully consumed by P2 before k_rowsort_key overwrites it.
  u64* stage = (u64*)(out + OUT_ES0);
  int use64 = (ws_size >= (size_t)WS_SCRATCH + 8ull * N_EDGES) ? 1 : 0;

  hipMemsetAsync(ws + WS_CNT, 0, 80000, stream);  // cnt + rankc (contiguous)

  int npair_b = (N_PAIRS + 255) / 256;
  k_rankhist<<<RANK_BLKS + HIST_BLKS, 256, 0, stream>>>(rankc, cnt,
                                                        (const int4*)e_i);
  k_scan_all<<<1, 1024, 0, stream>>>(rankc, sel, bn, out + OUT_BN, cnt, off,
                                     fill, fill1, selbits);
  if (use64) {
    int nblk1 = (N_EDGES + CHUNK - 1) / CHUNK;
    k_pairs_part1<<<nblk1 + npair_b, 256, 0, stream>>>(
        e_i, e_j, states, fill1, stage, bn, out + OUT_PAIRS0, nblk1);
    k_part2<<<nblk1, 256, 0, stream>>>(stage, fill, sk64);
    k_rowsort_key<<<N_NODES / RPB, 256, 0, stream>>>(sk64, off, times, selbits,
                                                     out);
  } else {
    k_pairs_part1<<<npair_b, 256, 0, stream>>>(
        e_i, e_j, states, fill1, stage, bn, out + OUT_PAIRS0, 0);
    k_scatter_idx<<<(N_EDGES / 4 + 255) / 256, 256, 0, stream>>>(
        (const int4*)e_i, fill, sk32);
    k_rowsort_idx<<<N_NODES, 256, 0, stream>>>(sk32, e_j, off, times, states,
                                               sel, out);
  }
}

// Round 10
// 358.990 us; speedup vs baseline: 1.2602x; 1.1680x over previous
//
#include <hip/hip_runtime.h>
#include <stdint.h>
#include <math.h>

#define N_NODES  10000
#define N_EDGES  5000000
#define BATCH    2000
#define N_PAIRS  1999000   // BATCH*(BATCH-1)/2

// Output offsets (float32 elements), concatenated in reference return order
#define OUT_BN      0
#define OUT_PAIRS0  2000
#define OUT_PAIRS1  2001000
#define OUT_ES0     4000000
#define OUT_ES1     9000000
#define OUT_T       14000000
#define OUT_S       19000000
#define OUT_M       24000000

// Workspace layout (bytes)
#define WS_KEYS     0          // fill1 lives here
#define WS_SEL      80000      // 10000 x i32
#define WS_BN       120000     // 2000  x i32
#define WS_CNT      128000     // 10000 x i32 (zeroed; aliased by selbits after k_scan_all)
#define WS_FILL     168000     // 10000 x i32 (rankc first, then fill; one 80KB memset covers CNT+FILL)
#define WS_OFF      208000     // 10001 x i32
#define WS_SCRATCH  248064     // 5M x u64 keys / 5M x u32 idx

// Sort key: (i<<38) | (j<<24) | (idx<<1) | state  (14+14+23+1 = 52 bits).
// Within a row i is constant, idx unique -> order == stable (j, idx).
// Intermediate (stage/sk) write order is nondeterministic (atomic races), but
// the final rank is by full unique key -> deterministic output.

#define RPB_LOG  7
#define NB1      79            // ceil(10000 / 128) coarse buckets
#define CHUNK    4096          // edges per partition block (256 thr x 16)
#define NBIN     192           // row-sort bins (adaptive shift keeps used bins <= 160)
#define NBITSW   313           // ceil(10000/32) sel bitmask words
#define RANK_BLKS 200          // 40 v-blocks x 5 key-chunks
#define HIST_BLKS 128          // grid-stride hist blocks

typedef unsigned long long u64;

// ---------------------------------------------------------------------------
__device__ __forceinline__ u64 score_key(int w, unsigned bits) {
  const float TINY = 1.17549435e-38f;
  float uf = __uint_as_float((bits >> 9) | 0x3f800000u) - 1.0f;
  float val = fmaxf(TINY, uf + TINY);
  float t1 = (float)log((double)val);            // inner log, rounded to f32
  float gmb = -(float)log((double)(-t1));        // outer log on f32-rounded input
  float score = (w > 0) ? ((float)log((double)w) + gmb) : (-INFINITY);
  unsigned fb = __float_as_uint(score);
  unsigned s = (fb & 0x80000000u) ? ~fb : (fb | 0x80000000u);
  unsigned d = ~s;
  return ((u64)d << 32) | (unsigned)w;
}

// JAX threefry2x32, partitionable mode: (x0,x1)=(0,v)+key; bits = out0^out1.
__device__ __forceinline__ u64 make_key(int v) {
  unsigned ks[3] = {0u, 19u, 0u ^ 19u ^ 0x1BD11BDAu};
  unsigned x0 = 0u + ks[0];
  unsigned x1 = (unsigned)v + ks[1];
  const int R0[4] = {13, 15, 26, 6};
  const int R1[4] = {17, 29, 16, 24};
#pragma unroll
  for (int g = 0; g < 5; ++g) {
    const int* R = (g & 1) ? R1 : R0;
#pragma unroll
    for (int r = 0; r < 4; ++r) {
      x0 += x1;
      x1 = (x1 << R[r]) | (x1 >> (32 - R[r]));
      x1 ^= x0;
    }
    x0 += ks[(g + 1) % 3];
    x1 += ks[(g + 2) % 3] + (unsigned)(g + 1);
  }
  return score_key(v, x0 ^ x1);
}

// Fused rank + hist. Blocks [0,200): partial rank — block (vblk,cblk) computes
// the 2048-key chunk cblk IN LDS and ranks its 256 v's against it; partial
// counts -> rankc. Blocks [200,200+HIST_BLKS): row histogram (grid-stride).
__global__ void __launch_bounds__(256) k_rankhist(
    int* __restrict__ rankc, int* __restrict__ cnt,
    const int4* __restrict__ e_i4) {
  __shared__ __align__(16) int sh4[N_NODES];   // 40000 B: lk[2048] u64 | h[10000]
  int tid = threadIdx.x;
  if ((int)blockIdx.x < RANK_BLKS) {
    u64* lk = (u64*)sh4;
    int vblk = blockIdx.x / 5, cblk = blockIdx.x % 5;
    int base = cblk * 2048;
    int lenc = min(2048, N_NODES - base);
    for (int t = tid; t < lenc; t += 256) lk[t] = make_key(base + t);
    __syncthreads();
    int v = vblk * 256 + tid;
    u64 kv = (v < N_NODES) ? make_key(v) : 0;
    int c = 0;
    for (int t = 0; t < lenc; ++t) c += (lk[t] < kv) ? 1 : 0;
    if (v < N_NODES && c) atomicAdd(&rankc[v], c);
  } else {
    int* h = sh4;
    for (int t = tid; t < N_NODES; t += 256) h[t] = 0;
    __syncthreads();
    int hb = blockIdx.x - RANK_BLKS;
    int stride = HIST_BLKS * 256;
    for (int t = hb * 256 + tid; t < N_EDGES / 4; t += stride) {
      int4 r = e_i4[t];
      atomicAdd(&h[r.x], 1);
      atomicAdd(&h[r.y], 1);
      atomicAdd(&h[r.z], 1);
      atomicAdd(&h[r.w], 1);
    }
    __syncthreads();
    for (int t = tid; t < N_NODES; t += 256) {
      int c = h[t];
      if (c) atomicAdd(&cnt[t], c);
    }
  }
}

// One block, 1024 threads; wave-shuffle scans.
// Phase 1: sel[i] = (rank < BATCH); compaction -> batch_nodes.
// Phase 2: exclusive scan cnt -> off; fill[i] = off[i]; seed coarse cursors.
//          NOTE: fill aliases rankc — all rankc reads are in phase 1 (pre-barrier).
// Phase 3: sel bitmask into selbits (aliases dead cnt).
__global__ void k_scan_all(const int* rankc, int* sel, int* bn, float* outbn,
                           const int* cnt, int* off, int* fill, int* fill1,
                           unsigned* selbits) {
  __shared__ int wsum[16];
  __shared__ unsigned lb[320];
  const int PER = 10;  // 1024*10 >= 10000
  int tid = threadIdx.x, lane = tid & 63, wid = tid >> 6;
  int base = tid * PER;
  int svv[PER];
  // ---- Phase 1 ----
  {
    int s = 0;
#pragma unroll
    for (int k = 0; k < PER; ++k) {
      int i = base + k;
      if (i < N_NODES) {
        int sv = (rankc[i] < BATCH) ? 1 : 0;
        sel[i] = sv;
        svv[k] = sv;
        s += sv;
      } else svv[k] = 0;
    }
    int inc = s;
#pragma unroll
    for (int d = 1; d < 64; d <<= 1) {
      int v = __shfl_up(inc, d, 64);
      if (lane >= d) inc += v;
    }
    if (lane == 63) wsum[wid] = inc;
    __syncthreads();
    int woff = 0;
    for (int w = 0; w < wid; ++w) woff += wsum[w];
    int run = woff + inc - s;
#pragma unroll
    for (int k = 0; k < PER; ++k) {
      int i = base + k;
      if (i < N_NODES && svv[k]) {
        bn[run] = i;
        outbn[run] = (float)i;
        ++run;
      }
    }
  }
  __syncthreads();   // wsum reuse + rankc fully read before fill writes
  // ---- Phase 2 ----
  {
    int cv[PER];
    int s = 0;
#pragma unroll
    for (int k = 0; k < PER; ++k) {
      int i = base + k;
      if (i < N_NODES) { cv[k] = cnt[i]; s += cv[k]; } else cv[k] = 0;
    }
    int inc = s;
#pragma unroll
    for (int d = 1; d < 64; d <<= 1) {
      int v = __shfl_up(inc, d, 64);
      if (lane >= d) inc += v;
    }
    if (lane == 63) wsum[wid] = inc;
    __syncthreads();
    int woff = 0;
    for (int w = 0; w < wid; ++w) woff += wsum[w];
    int run = woff + inc - s;
#pragma unroll
    for (int k = 0; k < PER; ++k) {
      int i = base + k;
      if (i < N_NODES) {
        off[i] = run;
        fill[i] = run;
        if ((i & ((1 << RPB_LOG) - 1)) == 0) fill1[i >> RPB_LOG] = run;
        run += cv[k];
      }
    }
    if (tid == 0) off[N_NODES] = N_EDGES;
  }
  // ---- Phase 3: bitmask (cnt fully consumed -> selbits may alias it) ----
  __syncthreads();
  if (tid < 320) lb[tid] = 0;
  __syncthreads();
#pragma unroll
  for (int k = 0; k < PER; ++k) {
    int i = base + k;
    if (i < N_NODES && svv[k]) atomicOr(&lb[i >> 5], 1u << (i & 31));
  }
  __syncthreads();
  if (tid < NBITSW) selbits[tid] = lb[tid];
}

// Fused: blocks [0,nblk1) = P1 coarse partition; blocks [nblk1, ...) = pairs.
// P1 v3: per-WAVE histograms + per-wave scatter cursors (folded back into h)
// to cut LDS same-address atomic contention 4x. LDS staging + coalesced drain
// retained (R3-proven vs direct scatter).
__global__ void __launch_bounds__(256) k_pairs_part1(
    const int* __restrict__ e_i, const int* __restrict__ e_j,
    const int* __restrict__ st, int* __restrict__ fill1,
    u64* __restrict__ stage, const int* __restrict__ bn,
    float* __restrict__ outp, int nblk1) {
  __shared__ u64 lkey[CHUNK];
  __shared__ int h[4][NB1];          // per-wave hist, then per-wave cursors
  __shared__ int bstart[NB1], basec[NB1];
  __shared__ int tcount_s;
  int tid = threadIdx.x, wid = tid >> 6;
  if ((int)blockIdx.x >= nblk1) {
    // ---- pairs ----
    int p = ((int)blockIdx.x - nblk1) * 256 + tid;
    if (p >= N_PAIRS) return;
    float tf = 2.0f * BATCH - 1.0f;
    float disc = tf * tf - 8.0f * (float)p;
    int ii = (int)((tf - sqrtf(disc)) * 0.5f);
    if (ii < 0) ii = 0;
    if (ii > BATCH - 2) ii = BATCH - 2;
    while (ii > 0 &&
           (long long)ii * (BATCH - 1) - (long long)ii * (ii - 1) / 2 > p) --ii;
    while ((long long)(ii + 1) * (BATCH - 1) - (long long)(ii + 1) * ii / 2 <= p) ++ii;
    long long S = (long long)ii * (BATCH - 1) - (long long)ii * (ii - 1) / 2;
    int jj = ii + 1 + (int)(p - S);
    outp[p] = (float)bn[ii];
    outp[N_PAIRS + p] = (float)bn[jj];
    return;
  }
  // ---- P1 ----
  int c0 = (int)blockIdx.x * CHUNK;
  int nloc = min(CHUNK, N_EDGES - c0);   // tail (2880) multiple of 4
  for (int t = tid; t < 4 * NB1; t += 256) ((int*)h)[t] = 0;
  __syncthreads();
  int iv[CHUNK / 256];
  const int4* e_i4 = (const int4*)(e_i + c0);
#pragma unroll
  for (int k = 0; k < CHUNK / 1024; ++k) {
    int q = tid + 256 * k;
    int ebase = 4 * q;
    if (ebase < nloc) {
      int4 r = e_i4[q];
      iv[4 * k + 0] = r.x; iv[4 * k + 1] = r.y;
      iv[4 * k + 2] = r.z; iv[4 * k + 3] = r.w;
      atomicAdd(&h[wid][r.x >> RPB_LOG], 1);
      atomicAdd(&h[wid][r.y >> RPB_LOG], 1);
      atomicAdd(&h[wid][r.z >> RPB_LOG], 1);
      atomicAdd(&h[wid][r.w >> RPB_LOG], 1);
    } else {
      iv[4 * k + 0] = iv[4 * k + 1] = iv[4 * k + 2] = iv[4 * k + 3] = -1;
    }
  }
  __syncthreads();
  // Wave 0: combine per-wave hists, exclusive scan (2 bins/lane), write
  // bstart + per-wave cursor starts back into h, reserve global runs.
  if (tid < 64) {
    int a0 = h[0][tid], a1 = h[1][tid], a2 = h[2][tid], a3 = h[3][tid];
    int a = a0 + a1 + a2 + a3;
    int b0 = 0, b1 = 0, b2 = 0, b3 = 0, b = 0;
    if (tid + 64 < NB1) {
      b0 = h[0][tid + 64]; b1 = h[1][tid + 64];
      b2 = h[2][tid + 64]; b3 = h[3][tid + 64];
      b = b0 + b1 + b2 + b3;
    }
    int inc0 = a;
#pragma unroll
    for (int d = 1; d < 64; d <<= 1) {
      int v = __shfl_up(inc0, d, 64);
      if (tid >= d) inc0 += v;
    }
    int t0 = __shfl(inc0, 63, 64);
    int inc1 = b;
#pragma unroll
    for (int d = 1; d < 64; d <<= 1) {
      int v = __shfl_up(inc1, d, 64);
      if (tid >= d) inc1 += v;
    }
    int tot = t0 + __shfl(inc1, 63, 64);
    int e0 = inc0 - a;
    bstart[tid] = e0;
    h[0][tid] = e0;
    h[1][tid] = e0 + a0;
    h[2][tid] = e0 + a0 + a1;
    h[3][tid] = e0 + a0 + a1 + a2;
    basec[tid] = a ? atomicAdd(&fill1[tid], a) : 0;
    if (tid + 64 < NB1) {
      int e1 = t0 + inc1 - b;
      bstart[tid + 64] = e1;
      h[0][tid + 64] = e1;
      h[1][tid + 64] = e1 + b0;
      h[2][tid + 64] = e1 + b0 + b1;
      h[3][tid + 64] = e1 + b0 + b1 + b2;
      basec[tid + 64] = b ? atomicAdd(&fill1[tid + 64], b) : 0;
    }
    if (tid == 0) tcount_s = tot;
  }
  __syncthreads();
  const int4* e_j4 = (const int4*)(e_j + c0);
  const int4* st4 = (const int4*)(st + c0);
#pragma unroll
  for (int k = 0; k < CHUNK / 1024; ++k) {
    int q = tid + 256 * k;
    int ebase = 4 * q;
    if (ebase < nloc) {
      int4 jj = e_j4[q];
      int4 ss = st4[q];
      int js[4] = {jj.x, jj.y, jj.z, jj.w};
      int s4[4] = {ss.x, ss.y, ss.z, ss.w};
#pragma unroll
      for (int c = 0; c < 4; ++c) {
        int i = iv[4 * k + c];
        unsigned e = (unsigned)(c0 + ebase + c);
        int b = i >> RPB_LOG;
        int pos = atomicAdd(&h[wid][b], 1);   // per-wave cursor
        lkey[pos] = ((u64)(unsigned)i << 38) | ((u64)(unsigned)js[c] << 24) |
                    ((u64)e << 1) | (u64)(unsigned)s4[c];
      }
    }
  }
  __syncthreads();
  int tcount = tcount_s;
  for (int t = tid; t < tcount; t += 256) {
    u64 kv = lkey[t];
    int b = (int)(kv >> (38 + RPB_LOG));
    stage[basec[b] + (t - bstart[b])] = kv;
  }
}

// P2 v3: fine partition, per-WAVE hist + cursors (folded into h) — same
// contention cut as P1. LDS staging + coalesced drain; wave-shuffle scan.
__global__ void __launch_bounds__(256) k_part2(
    const u64* __restrict__ stage, int* __restrict__ fill,
    u64* __restrict__ sk) {
  __shared__ u64 lkey[CHUNK];
  __shared__ int h[4][256];          // per-wave hist, then per-wave cursors
  __shared__ int bstart[256], baser[256], wsum4[4];
  __shared__ int rowbase_s;
  int tid = threadIdx.x, lane = tid & 63, wid = tid >> 6;
  int c0 = (int)blockIdx.x * CHUNK;
  int nloc = min(CHUNK, N_EDGES - c0);
  h[0][tid] = 0; h[1][tid] = 0; h[2][tid] = 0; h[3][tid] = 0;
  if (tid == 0)
    rowbase_s = ((int)(stage[c0] >> (38 + RPB_LOG))) << RPB_LOG;
  __syncthreads();
  int rowbase = rowbase_s;
  u64 kv[CHUNK / 256];
#pragma unroll
  for (int k = 0; k < CHUNK / 256; ++k) {
    int q = tid + 256 * k;
    if (q < nloc) {
      kv[k] = stage[c0 + q];
      atomicAdd(&h[wid][(int)(kv[k] >> 38) - rowbase], 1);
    }
  }
  __syncthreads();
  int h0 = h[0][tid], h1 = h[1][tid], h2 = h[2][tid], h3 = h[3][tid];
  int hv = h0 + h1 + h2 + h3;
  int inc = hv;
#pragma unroll
  for (int d = 1; d < 64; d <<= 1) {
    int v = __shfl_up(inc, d, 64);
    if (lane >= d) inc += v;
  }
  if (lane == 63) wsum4[wid] = inc;
  __syncthreads();   // wsum4 ready; all h reads complete
  int woff = 0;
  for (int w = 0; w < wid; ++w) woff += wsum4[w];
  int tcount = wsum4[0] + wsum4[1] + wsum4[2] + wsum4[3];
  int excl = woff + inc - hv;
  bstart[tid] = excl;
  h[0][tid] = excl;
  h[1][tid] = excl + h0;
  h[2][tid] = excl + h0 + h1;
  h[3][tid] = excl + h0 + h1 + h2;
  baser[tid] = hv ? atomicAdd(&fill[rowbase + tid], hv) : 0;
  __syncthreads();
#pragma unroll
  for (int k = 0; k < CHUNK / 256; ++k) {
    int q = tid + 256 * k;
    if (q < nloc) {
      int lr = (int)(kv[k] >> 38) - rowbase;
      int pos = atomicAdd(&h[wid][lr], 1);   // per-wave cursor
      lkey[pos] = kv[k];
    }
  }
  __syncthreads();
  for (int t = tid; t < tcount; t += 256) {
    u64 v = lkey[t];
    int lr = (int)(v >> 38) - rowbase;
    sk[baser[lr] + (t - bstart[lr])] = v;
  }
}

// Rowsort v7 (proven: 88-91 us, absmax 0 across R4/R7). Block-per-row,
// adaptive-shift bins + exact rank, in-place writeback, coalesced emit.
__global__ void __launch_bounds__(256) k_rowsort_key(
    const u64* __restrict__ sk, const int* __restrict__ off,
    const float* __restrict__ times, const unsigned* __restrict__ selbits,
    float* __restrict__ out) {
  __shared__ u64 buf[768];
  __shared__ int hist[NBIN], cur[NBIN];
  __shared__ unsigned bits[320];
  int tid = threadIdx.x;
  int row = blockIdx.x;
  int o0 = off[row], o1 = off[row + 1];
  int len = o1 - o0;
  if (len <= 0) return;
  if (len > 768) len = 768;   // rows are 500 +- 22; 768 = +12 sigma
  int span = N_NODES - 1 - row;       // j in [row+1, N_NODES-1]
  int s = 0;
  while ((span >> s) >= 160) ++s;     // bins used = ((span-1)>>s)+1 <= 160
  int mi = (int)((selbits[row >> 5] >> (row & 31)) & 1u);  // uniform broadcast
  for (int t = tid; t < NBIN; t += 256) hist[t] = 0;
  if (mi) {
    for (int t = tid; t < NBITSW; t += 256) bits[t] = selbits[t];
  }
  __syncthreads();   // B1
  // Load (strided, coalesced) into regs; histogram bins.
  u64 kv[3];
  int dv[3], rv[3];
  int jbase = row + 1;
#pragma unroll
  for (int k = 0; k < 3; ++k) {
    int t = tid + 256 * k;
    if (t < len) {
      u64 v = sk[o0 + t];
      kv[k] = v;
      int j = (int)((v >> 24) & 0x3FFFull);
      int d = (j - jbase) >> s;
      dv[k] = d;
      atomicAdd(&hist[d], 1);
    } else {
      dv[k] = -1;
    }
  }
  __syncthreads();   // B2
  // Exclusive scan of NBIN bins by wave 0 (3 bins/lane + shuffle scan).
  // hist <- excl start; cur <- excl start (becomes end after scatter).
  if (tid < 64) {
    int b0 = tid * 3;
    int c0 = hist[b0], c1 = hist[b0 + 1], c2 = hist[b0 + 2];
    int sum = c0 + c1 + c2;
    int inc = sum;
#pragma unroll
    for (int d = 1; d < 64; d <<= 1) {
      int v = __shfl_up(inc, d, 64);
      if (tid >= d) inc += v;
    }
    int excl = inc - sum;
    hist[b0] = excl;
    hist[b0 + 1] = excl + c0;
    hist[b0 + 2] = excl + c0 + c1;
    cur[b0] = excl;
    cur[b0 + 1] = excl + c0;
    cur[b0 + 2] = excl + c0 + c1;
  }
  __syncthreads();   // B3
  // Scatter into buckets (order within bucket arbitrary).
#pragma unroll
  for (int k = 0; k < 3; ++k) {
    if (dv[k] >= 0) {
      int pos = atomicAdd(&cur[dv[k]], 1);
      buf[pos] = kv[k];
    }
  }
  __syncthreads();   // B4
  // Rank within bucket by full key (keys unique); bounds: [hist[d], cur[d]).
#pragma unroll
  for (int k = 0; k < 3; ++k) {
    if (dv[k] >= 0) {
      u64 me = kv[k];
      int s0 = hist[dv[k]];
      int s1 = cur[dv[k]];
      int r = 0;
      for (int q = s0; q < s1; ++q) r += (buf[q] < me) ? 1 : 0;
      rv[k] = s0 + r;
    }
  }
  __syncthreads();   // B5: all rank reads done before in-place writeback
#pragma unroll
  for (int k = 0; k < 3; ++k)
    if (dv[k] >= 0) buf[rv[k]] = kv[k];
  __syncthreads();   // B6
  // Coalesced emit; fast path for unselected rows.
  float frow = (float)row;
  if (mi) {
    for (int t = tid; t < len; t += 256) {
      u64 k = buf[t];
      int j = (int)((k >> 24) & 0x3FFFull);
      int idx = (int)((k >> 1) & 0x7FFFFFull);
      int st = (int)(k & 1ull);
      int p = o0 + t;
      out[OUT_ES0 + p] = frow;
      out[OUT_ES1 + p] = (float)j;
      bool m = (bits[j >> 5] >> (j & 31)) & 1u;
      out[OUT_T + p] = m ? times[idx] : 0.0f;
      out[OUT_S + p] = m ? (float)st : 0.0f;
      out[OUT_M + p] = m ? 1.0f : 0.0f;
    }
  } else {
    for (int t = tid; t < len; t += 256) {
      u64 k = buf[t];
      int j = (int)((k >> 24) & 0x3FFFull);
      int p = o0 + t;
      out[OUT_ES0 + p] = frow;
      out[OUT_ES1 + p] = (float)j;
      out[OUT_T + p] = 0.0f;
      out[OUT_S + p] = 0.0f;
      out[OUT_M + p] = 0.0f;
    }
  }
}

// ---- Fallback path (ws too small for u64 keys): R4-style 4B idx scatter ----
__global__ void __launch_bounds__(256) k_scatter_idx(
    const int4* __restrict__ e_i4, int* __restrict__ fill,
    unsigned* __restrict__ sk) {
  int t = blockIdx.x * blockDim.x + threadIdx.x;
  if (t >= N_EDGES / 4) return;
  int4 r = e_i4[t];
  unsigned e = 4u * (unsigned)t;
  int c0 = atomicAdd(&fill[r.x], 1);
  int c1 = atomicAdd(&fill[r.y], 1);
  int c2 = atomicAdd(&fill[r.z], 1);
  int c3 = atomicAdd(&fill[r.w], 1);
  sk[c0] = e;
  sk[c1] = e + 1;
  sk[c2] = e + 2;
  sk[c3] = e + 3;
}

__global__ void __launch_bounds__(256) k_rowsort_idx(
    const unsigned* __restrict__ sk, const int* __restrict__ e_j_arr,
    const int* __restrict__ off, const float* __restrict__ times,
    const int* __restrict__ states, const int* __restrict__ sel,
    float* __restrict__ out) {
  __shared__ u64 key[2048];
  int row = blockIdx.x;
  int o0 = off[row], o1 = off[row + 1];
  int len = o1 - o0;
  if (len <= 0) return;
  if (len > 2048) len = 2048;
  int M = 2;
  while (M < len) M <<= 1;
  for (int t = threadIdx.x; t < M; t += blockDim.x) {
    if (t < len) {
      unsigned e = sk[o0 + t];
      key[t] = ((u64)(unsigned)e_j_arr[e] << 32) | e;
    } else {
      key[t] = 0xFFFFFFFFFFFFFFFFull;
    }
  }
  __syncthreads();
  for (int k = 2; k <= M; k <<= 1) {
    for (int j = k >> 1; j > 0; j >>= 1) {
      for (int t = threadIdx.x; t < M; t += blockDim.x) {
        int ixj = t ^ j;
        if (ixj > t) {
          u64 a = key[t], b = key[ixj];
          bool up = ((t & k) == 0);
          if (up ? (a > b) : (a < b)) {
            key[t] = b;
            key[ixj] = a;
          }
        }
      }
      __syncthreads();
    }
  }
  int mi = sel[row];
  float frow = (float)row;
  for (int t = threadIdx.x; t < len; t += blockDim.x) {
    u64 k = key[t];
    int j = (int)(k >> 32);
    int idx = (int)(k & 0xFFFFFFFFull);
    int p = o0 + t;
    out[OUT_ES0 + p] = frow;
    out[OUT_ES1 + p] = (float)j;
    bool m = (mi != 0) && (sel[j] != 0);
    float tm = 0.0f, sv = 0.0f;
    if (m) {
      tm = times[idx];
      sv = (float)states[idx];
    }
    out[OUT_T + p] = tm;
    out[OUT_S + p] = sv;
    out[OUT_M + p] = m ? 1.0f : 0.0f;
  }
}

extern "C" void kernel_launch(void* const* d_in, const int* in_sizes, int n_in,
                              void* d_out, int out_size, void* d_ws, size_t ws_size,
                              hipStream_t stream) {
  const int* edges = (const int*)d_in[0];       // (2, E): [0..E)=i, [E..2E)=j
  const float* times = (const float*)d_in[1];
  const int* states = (const int*)d_in[2];
  const int* e_i = edges;
  const int* e_j = edges + N_EDGES;
  float* out = (float*)d_out;
  char* ws = (char*)d_ws;

  int* fill1 = (int*)(ws + WS_KEYS);
  int* sel = (int*)(ws + WS_SEL);
  int* bn = (int*)(ws + WS_BN);
  int* cnt = (int*)(ws + WS_CNT);
  unsigned* selbits = (unsigned*)(ws + WS_CNT); // aliases cnt (dead after scan)
  int* fill = (int*)(ws + WS_FILL);
  int* rankc = (int*)(ws + WS_FILL);            // rankc aliases fill (phase-ordered)
  int* off = (int*)(ws + WS_OFF);
  u64* sk64 = (u64*)(ws + WS_SCRATCH);
  unsigned* sk32 = (unsigned*)(ws + WS_SCRATCH);
  // Staging buffer for P1 output: the es0/es1 output region (exactly 40 MB),
  // fully consumed by P2 before k_rowsort_key overwrites it.
  u64* stage = (u64*)(out + OUT_ES0);
  int use64 = (ws_size >= (size_t)WS_SCRATCH + 8ull * N_EDGES) ? 1 : 0;

  hipMemsetAsync(ws + WS_CNT, 0, 80000, stream);  // cnt + rankc (contiguous)

  int npair_b = (N_PAIRS + 255) / 256;
  k_rankhist<<<RANK_BLKS + HIST_BLKS, 256, 0, stream>>>(rankc, cnt,
                                                        (const int4*)e_i);
  k_scan_all<<<1, 1024, 0, stream>>>(rankc, sel, bn, out + OUT_BN, cnt, off,
                                     fill, fill1, selbits);
  if (use64) {
    int nblk1 = (N_EDGES + CHUNK - 1) / CHUNK;
    k_pairs_part1<<<nblk1 + npair_b, 256, 0, stream>>>(
        e_i, e_j, states, fill1, stage, bn, out + OUT_PAIRS0, nblk1);
    k_part2<<<nblk1, 256, 0, stream>>>(stage, fill, sk64);
    k_rowsort_key<<<N_NODES, 256, 0, stream>>>(sk64, off, times, selbits, out);
  } else {
    k_pairs_part1<<<npair_b, 256, 0, stream>>>(
        e_i, e_j, states, fill1, stage, bn, out + OUT_PAIRS0, 0);
    k_scatter_idx<<<(N_EDGES / 4 + 255) / 256, 256, 0, stream>>>(
        (const int4*)e_i, fill, sk32);
    k_rowsort_idx<<<N_NODES, 256, 0, stream>>>(sk32, e_j, off, times, states,
                                               sel, out);
  }
}

// Round 11
// 339.543 us; speedup vs baseline: 1.3324x; 1.0573x over previous
//
#include <hip/hip_runtime.h>
#include <stdint.h>
#include <math.h>

#define N_NODES  10000
#define N_EDGES  5000000
#define BATCH    2000
#define N_PAIRS  1999000   // BATCH*(BATCH-1)/2

// Output offsets (float32 elements), concatenated in reference return order
#define OUT_BN      0
#define OUT_PAIRS0  2000
#define OUT_PAIRS1  2001000
#define OUT_ES0     4000000
#define OUT_ES1     9000000
#define OUT_T       14000000
#define OUT_S       19000000
#define OUT_M       24000000

// Workspace layout (bytes)
#define WS_KEYS     0          // fill1 (79 ints) at +0; fill8 (1250 ints) at +4096
#define WS_SEL      80000      // 10000 x i32
#define WS_BN       120000     // 2000  x i32
#define WS_CNT      128000     // 10000 x i32 (zeroed; aliased by selbits after k_scan_all)
#define WS_FILL     168000     // 10000 x i32 (rankc first, then fill; one 80KB memset covers CNT+FILL)
#define WS_OFF      208000     // 10001 x i32
#define WS_SCRATCH  248064     // 5M x u64 keys / 5M x u32 idx

// Sort key: (i<<38) | (j<<24) | (idx<<1) | state  (14+14+23+1 = 52 bits).
// idx unique -> full-key order == (i, j, stable-original-position).
// Intermediate (stage/sk) write order is nondeterministic (atomic races), but
// the final rank is by full unique key -> deterministic output.

#define RPB_LOG  7
#define NB1      79            // ceil(10000 / 128) coarse buckets
#define CHUNK    4096          // edges per partition block (256 thr x 16)
#define NBITSW   313           // ceil(10000/32) sel bitmask words
#define RANK_BLKS 200          // 40 v-blocks x 5 key-chunks
#define HIST_BLKS 128          // grid-stride hist blocks
#define GRPLOG   3             // 8-row groups for part2/rowsort
#define NGRP     1250          // 10000 >> 3
#define GBINS    1024          // rowsort-8 bins: (row-r0)<<7 | inner(7b)
#define GCAP     4608          // group cap (avg 4000, +9.6 sigma)
#define KPT      18            // GCAP / 256

typedef unsigned long long u64;

// ---------------------------------------------------------------------------
__device__ __forceinline__ u64 score_key(int w, unsigned bits) {
  const float TINY = 1.17549435e-38f;
  float uf = __uint_as_float((bits >> 9) | 0x3f800000u) - 1.0f;
  float val = fmaxf(TINY, uf + TINY);
  float t1 = (float)log((double)val);            // inner log, rounded to f32
  float gmb = -(float)log((double)(-t1));        // outer log on f32-rounded input
  float score = (w > 0) ? ((float)log((double)w) + gmb) : (-INFINITY);
  unsigned fb = __float_as_uint(score);
  unsigned s = (fb & 0x80000000u) ? ~fb : (fb | 0x80000000u);
  unsigned d = ~s;
  return ((u64)d << 32) | (unsigned)w;
}

// JAX threefry2x32, partitionable mode: (x0,x1)=(0,v)+key; bits = out0^out1.
__device__ __forceinline__ u64 make_key(int v) {
  unsigned ks[3] = {0u, 19u, 0u ^ 19u ^ 0x1BD11BDAu};
  unsigned x0 = 0u + ks[0];
  unsigned x1 = (unsigned)v + ks[1];
  const int R0[4] = {13, 15, 26, 6};
  const int R1[4] = {17, 29, 16, 24};
#pragma unroll
  for (int g = 0; g < 5; ++g) {
    const int* R = (g & 1) ? R1 : R0;
#pragma unroll
    for (int r = 0; r < 4; ++r) {
      x0 += x1;
      x1 = (x1 << R[r]) | (x1 >> (32 - R[r]));
      x1 ^= x0;
    }
    x0 += ks[(g + 1) % 3];
    x1 += ks[(g + 2) % 3] + (unsigned)(g + 1);
  }
  return score_key(v, x0 ^ x1);
}

// Fused rank + hist. Blocks [0,200): partial rank — block (vblk,cblk) computes
// the 2048-key chunk cblk IN LDS and ranks its 256 v's against it; partial
// counts -> rankc. Blocks [200,200+HIST_BLKS): row histogram (grid-stride).
__global__ void __launch_bounds__(256) k_rankhist(
    int* __restrict__ rankc, int* __restrict__ cnt,
    const int4* __restrict__ e_i4) {
  __shared__ __align__(16) int sh4[N_NODES];   // 40000 B: lk[2048] u64 | h[10000]
  int tid = threadIdx.x;
  if ((int)blockIdx.x < RANK_BLKS) {
    u64* lk = (u64*)sh4;
    int vblk = blockIdx.x / 5, cblk = blockIdx.x % 5;
    int base = cblk * 2048;
    int lenc = min(2048, N_NODES - base);
    for (int t = tid; t < lenc; t += 256) lk[t] = make_key(base + t);
    __syncthreads();
    int v = vblk * 256 + tid;
    u64 kv = (v < N_NODES) ? make_key(v) : 0;
    int c = 0;
    for (int t = 0; t < lenc; ++t) c += (lk[t] < kv) ? 1 : 0;
    if (v < N_NODES && c) atomicAdd(&rankc[v], c);
  } else {
    int* h = sh4;
    for (int t = tid; t < N_NODES; t += 256) h[t] = 0;
    __syncthreads();
    int hb = blockIdx.x - RANK_BLKS;
    int stride = HIST_BLKS * 256;
    for (int t = hb * 256 + tid; t < N_EDGES / 4; t += stride) {
      int4 r = e_i4[t];
      atomicAdd(&h[r.x], 1);
      atomicAdd(&h[r.y], 1);
      atomicAdd(&h[r.z], 1);
      atomicAdd(&h[r.w], 1);
    }
    __syncthreads();
    for (int t = tid; t < N_NODES; t += 256) {
      int c = h[t];
      if (c) atomicAdd(&cnt[t], c);
    }
  }
}

// One block, 1024 threads; wave-shuffle scans.
// Phase 1: sel[i] = (rank < BATCH); compaction -> batch_nodes.
// Phase 2: exclusive scan cnt -> off; fill[i]=off[i] (fallback); seed fill1
//          (79 coarse) and fill8 (1250 group) cursors.
// Phase 3: sel bitmask into selbits (aliases dead cnt).
__global__ void k_scan_all(const int* rankc, int* sel, int* bn, float* outbn,
                           const int* cnt, int* off, int* fill, int* fill1,
                           int* fill8, unsigned* selbits) {
  __shared__ int wsum[16];
  __shared__ unsigned lb[320];
  const int PER = 10;  // 1024*10 >= 10000
  int tid = threadIdx.x, lane = tid & 63, wid = tid >> 6;
  int base = tid * PER;
  int svv[PER];
  // ---- Phase 1 ----
  {
    int s = 0;
#pragma unroll
    for (int k = 0; k < PER; ++k) {
      int i = base + k;
      if (i < N_NODES) {
        int sv = (rankc[i] < BATCH) ? 1 : 0;
        sel[i] = sv;
        svv[k] = sv;
        s += sv;
      } else svv[k] = 0;
    }
    int inc = s;
#pragma unroll
    for (int d = 1; d < 64; d <<= 1) {
      int v = __shfl_up(inc, d, 64);
      if (lane >= d) inc += v;
    }
    if (lane == 63) wsum[wid] = inc;
    __syncthreads();
    int woff = 0;
    for (int w = 0; w < wid; ++w) woff += wsum[w];
    int run = woff + inc - s;
#pragma unroll
    for (int k = 0; k < PER; ++k) {
      int i = base + k;
      if (i < N_NODES && svv[k]) {
        bn[run] = i;
        outbn[run] = (float)i;
        ++run;
      }
    }
  }
  __syncthreads();   // wsum reuse + rankc fully read before fill writes
  // ---- Phase 2 ----
  {
    int cv[PER];
    int s = 0;
#pragma unroll
    for (int k = 0; k < PER; ++k) {
      int i = base + k;
      if (i < N_NODES) { cv[k] = cnt[i]; s += cv[k]; } else cv[k] = 0;
    }
    int inc = s;
#pragma unroll
    for (int d = 1; d < 64; d <<= 1) {
      int v = __shfl_up(inc, d, 64);
      if (lane >= d) inc += v;
    }
    if (lane == 63) wsum[wid] = inc;
    __syncthreads();
    int woff = 0;
    for (int w = 0; w < wid; ++w) woff += wsum[w];
    int run = woff + inc - s;
#pragma unroll
    for (int k = 0; k < PER; ++k) {
      int i = base + k;
      if (i < N_NODES) {
        off[i] = run;
        fill[i] = run;                               // fallback path only
        if ((i & ((1 << RPB_LOG) - 1)) == 0) fill1[i >> RPB_LOG] = run;
        if ((i & ((1 << GRPLOG) - 1)) == 0) fill8[i >> GRPLOG] = run;
        run += cv[k];
      }
    }
    if (tid == 0) off[N_NODES] = N_EDGES;
  }
  // ---- Phase 3: bitmask (cnt fully consumed -> selbits may alias it) ----
  __syncthreads();
  if (tid < 320) lb[tid] = 0;
  __syncthreads();
#pragma unroll
  for (int k = 0; k < PER; ++k) {
    int i = base + k;
    if (i < N_NODES && svv[k]) atomicOr(&lb[i >> 5], 1u << (i & 31));
  }
  __syncthreads();
  if (tid < NBITSW) selbits[tid] = lb[tid];
}

// Fused: blocks [0,nblk1) = P1 coarse partition; blocks [nblk1, ...) = pairs.
// P1 (R10, proven): per-wave hist + cursors, LDS staging + coalesced drain.
__global__ void __launch_bounds__(256) k_pairs_part1(
    const int* __restrict__ e_i, const int* __restrict__ e_j,
    const int* __restrict__ st, int* __restrict__ fill1,
    u64* __restrict__ stage, const int* __restrict__ bn,
    float* __restrict__ outp, int nblk1) {
  __shared__ u64 lkey[CHUNK];
  __shared__ int h[4][NB1];          // per-wave hist, then per-wave cursors
  __shared__ int bstart[NB1], basec[NB1];
  __shared__ int tcount_s;
  int tid = threadIdx.x, wid = tid >> 6;
  if ((int)blockIdx.x >= nblk1) {
    // ---- pairs ----
    int p = ((int)blockIdx.x - nblk1) * 256 + tid;
    if (p >= N_PAIRS) return;
    float tf = 2.0f * BATCH - 1.0f;
    float disc = tf * tf - 8.0f * (float)p;
    int ii = (int)((tf - sqrtf(disc)) * 0.5f);
    if (ii < 0) ii = 0;
    if (ii > BATCH - 2) ii = BATCH - 2;
    while (ii > 0 &&
           (long long)ii * (BATCH - 1) - (long long)ii * (ii - 1) / 2 > p) --ii;
    while ((long long)(ii + 1) * (BATCH - 1) - (long long)(ii + 1) * ii / 2 <= p) ++ii;
    long long S = (long long)ii * (BATCH - 1) - (long long)ii * (ii - 1) / 2;
    int jj = ii + 1 + (int)(p - S);
    outp[p] = (float)bn[ii];
    outp[N_PAIRS + p] = (float)bn[jj];
    return;
  }
  // ---- P1 ----
  int c0 = (int)blockIdx.x * CHUNK;
  int nloc = min(CHUNK, N_EDGES - c0);   // tail (2880) multiple of 4
  for (int t = tid; t < 4 * NB1; t += 256) ((int*)h)[t] = 0;
  __syncthreads();
  int iv[CHUNK / 256];
  const int4* e_i4 = (const int4*)(e_i + c0);
#pragma unroll
  for (int k = 0; k < CHUNK / 1024; ++k) {
    int q = tid + 256 * k;
    int ebase = 4 * q;
    if (ebase < nloc) {
      int4 r = e_i4[q];
      iv[4 * k + 0] = r.x; iv[4 * k + 1] = r.y;
      iv[4 * k + 2] = r.z; iv[4 * k + 3] = r.w;
      atomicAdd(&h[wid][r.x >> RPB_LOG], 1);
      atomicAdd(&h[wid][r.y >> RPB_LOG], 1);
      atomicAdd(&h[wid][r.z >> RPB_LOG], 1);
      atomicAdd(&h[wid][r.w >> RPB_LOG], 1);
    } else {
      iv[4 * k + 0] = iv[4 * k + 1] = iv[4 * k + 2] = iv[4 * k + 3] = -1;
    }
  }
  __syncthreads();
  // Wave 0: combine per-wave hists, exclusive scan (2 bins/lane), write
  // bstart + per-wave cursor starts back into h, reserve global runs.
  if (tid < 64) {
    int a0 = h[0][tid], a1 = h[1][tid], a2 = h[2][tid], a3 = h[3][tid];
    int a = a0 + a1 + a2 + a3;
    int b0 = 0, b1 = 0, b2 = 0, b3 = 0, b = 0;
    if (tid + 64 < NB1) {
      b0 = h[0][tid + 64]; b1 = h[1][tid + 64];
      b2 = h[2][tid + 64]; b3 = h[3][tid + 64];
      b = b0 + b1 + b2 + b3;
    }
    int inc0 = a;
#pragma unroll
    for (int d = 1; d < 64; d <<= 1) {
      int v = __shfl_up(inc0, d, 64);
      if (tid >= d) inc0 += v;
    }
    int t0 = __shfl(inc0, 63, 64);
    int inc1 = b;
#pragma unroll
    for (int d = 1; d < 64; d <<= 1) {
      int v = __shfl_up(inc1, d, 64);
      if (tid >= d) inc1 += v;
    }
    int tot = t0 + __shfl(inc1, 63, 64);
    int e0 = inc0 - a;
    bstart[tid] = e0;
    h[0][tid] = e0;
    h[1][tid] = e0 + a0;
    h[2][tid] = e0 + a0 + a1;
    h[3][tid] = e0 + a0 + a1 + a2;
    basec[tid] = a ? atomicAdd(&fill1[tid], a) : 0;
    if (tid + 64 < NB1) {
      int e1 = t0 + inc1 - b;
      bstart[tid + 64] = e1;
      h[0][tid + 64] = e1;
      h[1][tid + 64] = e1 + b0;
      h[2][tid + 64] = e1 + b0 + b1;
      h[3][tid + 64] = e1 + b0 + b1 + b2;
      basec[tid + 64] = b ? atomicAdd(&fill1[tid + 64], b) : 0;
    }
    if (tid == 0) tcount_s = tot;
  }
  __syncthreads();
  const int4* e_j4 = (const int4*)(e_j + c0);
  const int4* st4 = (const int4*)(st + c0);
#pragma unroll
  for (int k = 0; k < CHUNK / 1024; ++k) {
    int q = tid + 256 * k;
    int ebase = 4 * q;
    if (ebase < nloc) {
      int4 jj = e_j4[q];
      int4 ss = st4[q];
      int js[4] = {jj.x, jj.y, jj.z, jj.w};
      int s4[4] = {ss.x, ss.y, ss.z, ss.w};
#pragma unroll
      for (int c = 0; c < 4; ++c) {
        int i = iv[4 * k + c];
        unsigned e = (unsigned)(c0 + ebase + c);
        int b = i >> RPB_LOG;
        int pos = atomicAdd(&h[wid][b], 1);   // per-wave cursor
        lkey[pos] = ((u64)(unsigned)i << 38) | ((u64)(unsigned)js[c] << 24) |
                    ((u64)e << 1) | (u64)(unsigned)s4[c];
      }
    }
  }
  __syncthreads();
  int tcount = tcount_s;
  for (int t = tid; t < tcount; t += 256) {
    u64 kv = lkey[t];
    int b = (int)(kv >> (38 + RPB_LOG));
    stage[basec[b] + (t - bstart[b])] = kv;
  }
}

// P2 v4: fine partition into 8-row GROUPS (1250 cursors) instead of rows.
// Chunk window = exactly 32 groups (rowbase is 8-aligned, rows < rowbase+256).
// Drain runs grow 16 -> ~128 contiguous elements (1 KB) per group per chunk.
// Per-wave hist + cursors (R10-proven). Rowsort-8 full-sorts each group, so
// arbitrary order within the group slot is fine.
__global__ void __launch_bounds__(256) k_part2(
    const u64* __restrict__ stage, int* __restrict__ fill8,
    u64* __restrict__ sk) {
  __shared__ u64 lkey[CHUNK];
  __shared__ int h[4][32];           // per-wave hist, then per-wave cursors
  __shared__ int bstart[32], baser8[32];
  __shared__ int rowbase_s;
  int tid = threadIdx.x, wid = tid >> 6;
  int c0 = (int)blockIdx.x * CHUNK;
  int nloc = min(CHUNK, N_EDGES - c0);
  if (tid < 128) ((int*)h)[tid] = 0;
  if (tid == 0)
    rowbase_s = ((int)(stage[c0] >> (38 + RPB_LOG))) << RPB_LOG;
  __syncthreads();
  int rowbase = rowbase_s;
  int grp0 = rowbase >> GRPLOG;
  u64 kv[CHUNK / 256];
#pragma unroll
  for (int k = 0; k < CHUNK / 256; ++k) {
    int q = tid + 256 * k;
    if (q < nloc) {
      kv[k] = stage[c0 + q];
      int g = ((int)(kv[k] >> 38) - rowbase) >> GRPLOG;   // 0..31
      atomicAdd(&h[wid][g], 1);
    }
  }
  __syncthreads();
  // Wave 0: lanes 0..31 own one group each; scan + cursors + reservations.
  if (tid < 64) {
    int b = tid;
    int a0 = 0, a1 = 0, a2 = 0, a3 = 0, a = 0;
    if (b < 32) {
      a0 = h[0][b]; a1 = h[1][b]; a2 = h[2][b]; a3 = h[3][b];
      a = a0 + a1 + a2 + a3;
    }
    int inc = a;
#pragma unroll
    for (int d = 1; d < 64; d <<= 1) {
      int v = __shfl_up(inc, d, 64);
      if (tid >= d) inc += v;
    }
    int excl = inc - a;
    if (b < 32) {
      bstart[b] = excl;
      h[0][b] = excl;
      h[1][b] = excl + a0;
      h[2][b] = excl + a0 + a1;
      h[3][b] = excl + a0 + a1 + a2;
      baser8[b] = a ? atomicAdd(&fill8[grp0 + b], a) : 0;
    }
  }
  __syncthreads();
#pragma unroll
  for (int k = 0; k < CHUNK / 256; ++k) {
    int q = tid + 256 * k;
    if (q < nloc) {
      int g = ((int)(kv[k] >> 38) - rowbase) >> GRPLOG;
      int pos = atomicAdd(&h[wid][g], 1);   // per-wave cursor
      lkey[pos] = kv[k];
    }
  }
  __syncthreads();
  for (int t = tid; t < nloc; t += 256) {
    u64 v = lkey[t];
    int g = ((int)(v >> 38) - rowbase) >> GRPLOG;
    sk[baser8[g] + (t - bstart[g])] = v;
  }
}

// Rowsort-8: one 8-row group (~4000 keys) per block (grid 1250). Full-key
// sort of the group = concatenated sorted rows (v10-proven emit pattern).
// Bin d = (row-r0)<<7 | ((key38 - jbase<<24) >> sh_row), sh_row adaptive
// (17 + ceil_log2(span)) -> <=128 bins/row, ~4-8 keys/bin even for tail rows
// (idx bits split duplicate-j runs). v7's phase pipeline, fixed costs /8.
__global__ void __launch_bounds__(256) k_rowsort_key(
    const u64* __restrict__ sk, const int* __restrict__ off,
    const float* __restrict__ times, const unsigned* __restrict__ selbits,
    float* __restrict__ out) {
  __shared__ u64 buf[GCAP];
  __shared__ int hist[GBINS], cur[GBINS];
  __shared__ unsigned bits[320];
  __shared__ int wsum4[4];
  int tid = threadIdx.x, lane = tid & 63, wid = tid >> 6;
  int r0 = (int)blockIdx.x << GRPLOG;
  int o0 = off[r0], o1 = off[r0 + (1 << GRPLOG)];
  int blen = o1 - o0;
  if (blen <= 0) return;
  if (blen > GCAP) blen = GCAP;   // avg 4000, +9.6 sigma: unreachable
  // Issue key loads first (HBM latency overlaps LDS init).
  u64 kv[KPT];
  int dv[KPT], rv[KPT];
#pragma unroll
  for (int k = 0; k < KPT; ++k) {
    int t = tid + 256 * k;
    kv[k] = (t < blen) ? sk[o0 + t] : 0;
  }
  for (int t = tid; t < GBINS; t += 256) hist[t] = 0;
  for (int t = tid; t < NBITSW; t += 256) bits[t] = selbits[t];
  __syncthreads();   // B1
  // Bin + histogram.
#pragma unroll
  for (int k = 0; k < KPT; ++k) {
    int t = tid + 256 * k;
    if (t < blen) {
      u64 v = kv[k];
      int row = (int)(v >> 38);
      int span = N_NODES - 1 - row;                    // >= 1
      int sh = 17 + ((span > 1) ? (32 - __clz(span - 1)) : 0);
      u64 rel = (v & 0x3FFFFFFFFFull) - ((u64)(row + 1) << 24);
      int d = ((row - r0) << 7) | (int)(rel >> sh);    // inner < 128
      dv[k] = d;
      atomicAdd(&hist[d], 1);
    } else {
      dv[k] = -1;
    }
  }
  __syncthreads();   // B2
  // Block-wide exclusive scan of 1024 bins (4 consecutive per thread).
  {
    int b4 = tid * 4;
    int c0 = hist[b4], c1 = hist[b4 + 1], c2 = hist[b4 + 2], c3 = hist[b4 + 3];
    int sum = c0 + c1 + c2 + c3;
    int inc = sum;
#pragma unroll
    for (int d = 1; d < 64; d <<= 1) {
      int v = __shfl_up(inc, d, 64);
      if (lane >= d) inc += v;
    }
    if (lane == 63) wsum4[wid] = inc;
    __syncthreads();   // B3
    int woff = 0;
    for (int w = 0; w < wid; ++w) woff += wsum4[w];
    int excl = woff + inc - sum;
    hist[b4] = excl;                 cur[b4] = excl;
    hist[b4 + 1] = excl + c0;        cur[b4 + 1] = excl + c0;
    hist[b4 + 2] = excl + c0 + c1;   cur[b4 + 2] = excl + c0 + c1;
    hist[b4 + 3] = excl + c0 + c1 + c2;
    cur[b4 + 3] = excl + c0 + c1 + c2;
  }
  __syncthreads();   // B4
  // Scatter into bins (order within bin arbitrary).
#pragma unroll
  for (int k = 0; k < KPT; ++k) {
    if (dv[k] >= 0) {
      int pos = atomicAdd(&cur[dv[k]], 1);
      buf[pos] = kv[k];
    }
  }
  __syncthreads();   // B5
  // Rank within bin [hist[d], cur[d]) by full key (unique).
#pragma unroll
  for (int k = 0; k < KPT; ++k) {
    if (dv[k] >= 0) {
      u64 me = kv[k];
      int s0 = hist[dv[k]];
      int s1 = cur[dv[k]];
      int r = 0;
      for (int q = s0; q < s1; ++q) r += (buf[q] < me) ? 1 : 0;
      rv[k] = s0 + r;
    }
  }
  __syncthreads();   // B6: rank reads done before in-place writeback
#pragma unroll
  for (int k = 0; k < KPT; ++k)
    if (dv[k] >= 0) buf[rv[k]] = kv[k];
  __syncthreads();   // B7
  // Coalesced emit (v10-proven pattern; row decoded from key).
  for (int t = tid; t < blen; t += 256) {
    u64 k = buf[t];
    int row = (int)(k >> 38);
    int j = (int)((k >> 24) & 0x3FFFull);
    int idx = (int)((k >> 1) & 0x7FFFFFull);
    int p = o0 + t;
    out[OUT_ES0 + p] = (float)row;
    out[OUT_ES1 + p] = (float)j;
    bool m = ((bits[row >> 5] >> (row & 31)) & 1u) &&
             ((bits[j >> 5] >> (j & 31)) & 1u);
    out[OUT_T + p] = m ? times[idx] : 0.0f;
    out[OUT_S + p] = m ? (float)(int)(k & 1ull) : 0.0f;
    out[OUT_M + p] = m ? 1.0f : 0.0f;
  }
}

// ---- Fallback path (ws too small for u64 keys): R4-style 4B idx scatter ----
__global__ void __launch_bounds__(256) k_scatter_idx(
    const int4* __restrict__ e_i4, int* __restrict__ fill,
    unsigned* __restrict__ sk) {
  int t = blockIdx.x * blockDim.x + threadIdx.x;
  if (t >= N_EDGES / 4) return;
  int4 r = e_i4[t];
  unsigned e = 4u * (unsigned)t;
  int c0 = atomicAdd(&fill[r.x], 1);
  int c1 = atomicAdd(&fill[r.y], 1);
  int c2 = atomicAdd(&fill[r.z], 1);
  int c3 = atomicAdd(&fill[r.w], 1);
  sk[c0] = e;
  sk[c1] = e + 1;
  sk[c2] = e + 2;
  sk[c3] = e + 3;
}

__global__ void __launch_bounds__(256) k_rowsort_idx(
    const unsigned* __restrict__ sk, const int* __restrict__ e_j_arr,
    const int* __restrict__ off, const float* __restrict__ times,
    const int* __restrict__ states, const int* __restrict__ sel,
    float* __restrict__ out) {
  __shared__ u64 key[2048];
  int row = blockIdx.x;
  int o0 = off[row], o1 = off[row + 1];
  int len = o1 - o0;
  if (len <= 0) return;
  if (len > 2048) len = 2048;
  int M = 2;
  while (M < len) M <<= 1;
  for (int t = threadIdx.x; t < M; t += blockDim.x) {
    if (t < len) {
      unsigned e = sk[o0 + t];
      key[t] = ((u64)(unsigned)e_j_arr[e] << 32) | e;
    } else {
      key[t] = 0xFFFFFFFFFFFFFFFFull;
    }
  }
  __syncthreads();
  for (int k = 2; k <= M; k <<= 1) {
    for (int j = k >> 1; j > 0; j >>= 1) {
      for (int t = threadIdx.x; t < M; t += blockDim.x) {
        int ixj = t ^ j;
        if (ixj > t) {
          u64 a = key[t], b = key[ixj];
          bool up = ((t & k) == 0);
          if (up ? (a > b) : (a < b)) {
            key[t] = b;
            key[ixj] = a;
          }
        }
      }
      __syncthreads();
    }
  }
  int mi = sel[row];
  float frow = (float)row;
  for (int t = threadIdx.x; t < len; t += blockDim.x) {
    u64 k = key[t];
    int j = (int)(k >> 32);
    int idx = (int)(k & 0xFFFFFFFFull);
    int p = o0 + t;
    out[OUT_ES0 + p] = frow;
    out[OUT_ES1 + p] = (float)j;
    bool m = (mi != 0) && (sel[j] != 0);
    float tm = 0.0f, sv = 0.0f;
    if (m) {
      tm = times[idx];
      sv = (float)states[idx];
    }
    out[OUT_T + p] = tm;
    out[OUT_S + p] = sv;
    out[OUT_M + p] = m ? 1.0f : 0.0f;
  }
}

extern "C" void kernel_launch(void* const* d_in, const int* in_sizes, int n_in,
                              void* d_out, int out_size, void* d_ws, size_t ws_size,
                              hipStream_t stream) {
  const int* edges = (const int*)d_in[0];       // (2, E): [0..E)=i, [E..2E)=j
  const float* times = (const float*)d_in[1];
  const int* states = (const int*)d_in[2];
  const int* e_i = edges;
  const int* e_j = edges + N_EDGES;
  float* out = (float*)d_out;
  char* ws = (char*)d_ws;

  int* fill1 = (int*)(ws + WS_KEYS);            // 79 ints
  int* fill8 = (int*)(ws + WS_KEYS + 4096);     // 1250 ints (same dead region)
  int* sel = (int*)(ws + WS_SEL);
  int* bn = (int*)(ws + WS_BN);
  int* cnt = (int*)(ws + WS_CNT);
  unsigned* selbits = (unsigned*)(ws + WS_CNT); // aliases cnt (dead after scan)
  int* fill = (int*)(ws + WS_FILL);
  int* rankc = (int*)(ws + WS_FILL);            // rankc aliases fill (phase-ordered)
  int* off = (int*)(ws + WS_OFF);
  u64* sk64 = (u64*)(ws + WS_SCRATCH);
  unsigned* sk32 = (unsigned*)(ws + WS_SCRATCH);
  // Staging buffer for P1 output: the es0/es1 output region (exactly 40 MB),
  // fully consumed by P2 before k_rowsort_key overwrites it.
  u64* stage = (u64*)(out + OUT_ES0);
  int use64 = (ws_size >= (size_t)WS_SCRATCH + 8ull * N_EDGES) ? 1 : 0;

  hipMemsetAsync(ws + WS_CNT, 0, 80000, stream);  // cnt + rankc (contiguous)

  int npair_b = (N_PAIRS + 255) / 256;
  k_rankhist<<<RANK_BLKS + HIST_BLKS, 256, 0, stream>>>(rankc, cnt,
                                                        (const int4*)e_i);
  k_scan_all<<<1, 1024, 0, stream>>>(rankc, sel, bn, out + OUT_BN, cnt, off,
                                     fill, fill1, fill8, selbits);
  if (use64) {
    int nblk1 = (N_EDGES + CHUNK - 1) / CHUNK;
    k_pairs_part1<<<nblk1 + npair_b, 256, 0, stream>>>(
        e_i, e_j, states, fill1, stage, bn, out + OUT_PAIRS0, nblk1);
    k_part2<<<nblk1, 256, 0, stream>>>(stage, fill8, sk64);
    k_rowsort_key<<<NGRP, 256, 0, stream>>>(sk64, off, times, selbits, out);
  } else {
    k_pairs_part1<<<npair_b, 256, 0, stream>>>(
        e_i, e_j, states, fill1, stage, bn, out + OUT_PAIRS0, 0);
    k_scatter_idx<<<(N_EDGES / 4 + 255) / 256, 256, 0, stream>>>(
        (const int4*)e_i, fill, sk32);
    k_rowsort_idx<<<N_NODES, 256, 0, stream>>>(sk32, e_j, off, times, states,
                                               sel, out);
  }
}

// Round 12
// 326.355 us; speedup vs baseline: 1.3862x; 1.0404x over previous
//
#include <hip/hip_runtime.h>
#include <stdint.h>
#include <math.h>

#define N_NODES  10000
#define N_EDGES  5000000
#define BATCH    2000
#define N_PAIRS  1999000   // BATCH*(BATCH-1)/2

// Output offsets (float32 elements), concatenated in reference return order
#define OUT_BN      0
#define OUT_PAIRS0  2000
#define OUT_PAIRS1  2001000
#define OUT_ES0     4000000
#define OUT_ES1     9000000
#define OUT_T       14000000
#define OUT_S       19000000
#define OUT_M       24000000

// Workspace layout (bytes)
#define WS_KEYS     0          // fill1 (79 ints) at +0; fill8 (2500 ints) at +4096
#define WS_SEL      80000      // 10000 x i32
#define WS_BN       120000     // 2000  x i32
#define WS_CNT      128000     // 10000 x i32 (zeroed; aliased by selbits after k_scan_all)
#define WS_FILL     168000     // 10000 x i32 (rankc first, then fill; one 80KB memset covers CNT+FILL)
#define WS_OFF      208000     // 10001 x i32
#define WS_SCRATCH  248064     // 5M x u64 keys / 5M x u32 idx

// Sort key: (i<<38) | (j<<24) | (idx<<1) | state  (14+14+23+1 = 52 bits).
// idx unique -> full-key order == (i, j, stable-original-position).
// Intermediate (stage/sk) write order is nondeterministic (atomic races), but
// the final rank is by full unique key -> deterministic output.

#define RPB_LOG  7
#define NB1      79            // ceil(10000 / 128) coarse buckets
#define CHUNK    4096          // edges per partition block (256 thr x 16)
#define NBITSW   313           // ceil(10000/32) sel bitmask words
#define RANK_BLKS 200          // 40 v-blocks x 5 key-chunks
#define HIST_BLKS 128          // grid-stride hist blocks
#define GRPLOG   2             // 4-row groups for part2/rowsort (R11 was 3)
#define NGRP     2500          // 10000 >> 2
#define NGCHUNK  64            // groups per part2 chunk window (256 rows)
#define GBINS    512           // rowsort bins: (row-r0)<<7 | inner(7b)
#define GCAP     2304          // group cap (avg 2000, +6.8 sigma)
#define KPT      9             // GCAP / 256

typedef unsigned long long u64;

// ---------------------------------------------------------------------------
__device__ __forceinline__ u64 score_key(int w, unsigned bits) {
  const float TINY = 1.17549435e-38f;
  float uf = __uint_as_float((bits >> 9) | 0x3f800000u) - 1.0f;
  float val = fmaxf(TINY, uf + TINY);
  float t1 = (float)log((double)val);            // inner log, rounded to f32
  float gmb = -(float)log((double)(-t1));        // outer log on f32-rounded input
  float score = (w > 0) ? ((float)log((double)w) + gmb) : (-INFINITY);
  unsigned fb = __float_as_uint(score);
  unsigned s = (fb & 0x80000000u) ? ~fb : (fb | 0x80000000u);
  unsigned d = ~s;
  return ((u64)d << 32) | (unsigned)w;
}

// JAX threefry2x32, partitionable mode: (x0,x1)=(0,v)+key; bits = out0^out1.
__device__ __forceinline__ u64 make_key(int v) {
  unsigned ks[3] = {0u, 19u, 0u ^ 19u ^ 0x1BD11BDAu};
  unsigned x0 = 0u + ks[0];
  unsigned x1 = (unsigned)v + ks[1];
  const int R0[4] = {13, 15, 26, 6};
  const int R1[4] = {17, 29, 16, 24};
#pragma unroll
  for (int g = 0; g < 5; ++g) {
    const int* R = (g & 1) ? R1 : R0;
#pragma unroll
    for (int r = 0; r < 4; ++r) {
      x0 += x1;
      x1 = (x1 << R[r]) | (x1 >> (32 - R[r]));
      x1 ^= x0;
    }
    x0 += ks[(g + 1) % 3];
    x1 += ks[(g + 2) % 3] + (unsigned)(g + 1);
  }
  return score_key(v, x0 ^ x1);
}

// Fused rank + hist. Blocks [0,200): partial rank — block (vblk,cblk) computes
// the 2048-key chunk cblk IN LDS and ranks its 256 v's against it; partial
// counts -> rankc. Blocks [200,200+HIST_BLKS): row histogram (grid-stride).
__global__ void __launch_bounds__(256) k_rankhist(
    int* __restrict__ rankc, int* __restrict__ cnt,
    const int4* __restrict__ e_i4) {
  __shared__ __align__(16) int sh4[N_NODES];   // 40000 B: lk[2048] u64 | h[10000]
  int tid = threadIdx.x;
  if ((int)blockIdx.x < RANK_BLKS) {
    u64* lk = (u64*)sh4;
    int vblk = blockIdx.x / 5, cblk = blockIdx.x % 5;
    int base = cblk * 2048;
    int lenc = min(2048, N_NODES - base);
    for (int t = tid; t < lenc; t += 256) lk[t] = make_key(base + t);
    __syncthreads();
    int v = vblk * 256 + tid;
    u64 kv = (v < N_NODES) ? make_key(v) : 0;
    int c = 0;
    for (int t = 0; t < lenc; ++t) c += (lk[t] < kv) ? 1 : 0;
    if (v < N_NODES && c) atomicAdd(&rankc[v], c);
  } else {
    int* h = sh4;
    for (int t = tid; t < N_NODES; t += 256) h[t] = 0;
    __syncthreads();
    int hb = blockIdx.x - RANK_BLKS;
    int stride = HIST_BLKS * 256;
    for (int t = hb * 256 + tid; t < N_EDGES / 4; t += stride) {
      int4 r = e_i4[t];
      atomicAdd(&h[r.x], 1);
      atomicAdd(&h[r.y], 1);
      atomicAdd(&h[r.z], 1);
      atomicAdd(&h[r.w], 1);
    }
    __syncthreads();
    for (int t = tid; t < N_NODES; t += 256) {
      int c = h[t];
      if (c) atomicAdd(&cnt[t], c);
    }
  }
}

// One block, 1024 threads; wave-shuffle scans.
// Phase 1: sel[i] = (rank < BATCH); compaction -> batch_nodes.
// Phase 2: exclusive scan cnt -> off; fill[i]=off[i] (fallback); seed fill1
//          (79 coarse) and fill8 (2500 group) cursors.
// Phase 3: sel bitmask into selbits (aliases dead cnt).
__global__ void k_scan_all(const int* rankc, int* sel, int* bn, float* outbn,
                           const int* cnt, int* off, int* fill, int* fill1,
                           int* fill8, unsigned* selbits) {
  __shared__ int wsum[16];
  __shared__ unsigned lb[320];
  const int PER = 10;  // 1024*10 >= 10000
  int tid = threadIdx.x, lane = tid & 63, wid = tid >> 6;
  int base = tid * PER;
  int svv[PER];
  // ---- Phase 1 ----
  {
    int s = 0;
#pragma unroll
    for (int k = 0; k < PER; ++k) {
      int i = base + k;
      if (i < N_NODES) {
        int sv = (rankc[i] < BATCH) ? 1 : 0;
        sel[i] = sv;
        svv[k] = sv;
        s += sv;
      } else svv[k] = 0;
    }
    int inc = s;
#pragma unroll
    for (int d = 1; d < 64; d <<= 1) {
      int v = __shfl_up(inc, d, 64);
      if (lane >= d) inc += v;
    }
    if (lane == 63) wsum[wid] = inc;
    __syncthreads();
    int woff = 0;
    for (int w = 0; w < wid; ++w) woff += wsum[w];
    int run = woff + inc - s;
#pragma unroll
    for (int k = 0; k < PER; ++k) {
      int i = base + k;
      if (i < N_NODES && svv[k]) {
        bn[run] = i;
        outbn[run] = (float)i;
        ++run;
      }
    }
  }
  __syncthreads();   // wsum reuse + rankc fully read before fill writes
  // ---- Phase 2 ----
  {
    int cv[PER];
    int s = 0;
#pragma unroll
    for (int k = 0; k < PER; ++k) {
      int i = base + k;
      if (i < N_NODES) { cv[k] = cnt[i]; s += cv[k]; } else cv[k] = 0;
    }
    int inc = s;
#pragma unroll
    for (int d = 1; d < 64; d <<= 1) {
      int v = __shfl_up(inc, d, 64);
      if (lane >= d) inc += v;
    }
    if (lane == 63) wsum[wid] = inc;
    __syncthreads();
    int woff = 0;
    for (int w = 0; w < wid; ++w) woff += wsum[w];
    int run = woff + inc - s;
#pragma unroll
    for (int k = 0; k < PER; ++k) {
      int i = base + k;
      if (i < N_NODES) {
        off[i] = run;
        fill[i] = run;                               // fallback path only
        if ((i & ((1 << RPB_LOG) - 1)) == 0) fill1[i >> RPB_LOG] = run;
        if ((i & ((1 << GRPLOG) - 1)) == 0) fill8[i >> GRPLOG] = run;
        run += cv[k];
      }
    }
    if (tid == 0) off[N_NODES] = N_EDGES;
  }
  // ---- Phase 3: bitmask (cnt fully consumed -> selbits may alias it) ----
  __syncthreads();
  if (tid < 320) lb[tid] = 0;
  __syncthreads();
#pragma unroll
  for (int k = 0; k < PER; ++k) {
    int i = base + k;
    if (i < N_NODES && svv[k]) atomicOr(&lb[i >> 5], 1u << (i & 31));
  }
  __syncthreads();
  if (tid < NBITSW) selbits[tid] = lb[tid];
}

// Fused: blocks [0,nblk1) = P1 coarse partition; blocks [nblk1, ...) = pairs.
// P1 (R10, proven): per-wave hist + cursors, LDS staging + coalesced drain.
__global__ void __launch_bounds__(256) k_pairs_part1(
    const int* __restrict__ e_i, const int* __restrict__ e_j,
    const int* __restrict__ st, int* __restrict__ fill1,
    u64* __restrict__ stage, const int* __restrict__ bn,
    float* __restrict__ outp, int nblk1) {
  __shared__ u64 lkey[CHUNK];
  __shared__ int h[4][NB1];          // per-wave hist, then per-wave cursors
  __shared__ int bstart[NB1], basec[NB1];
  __shared__ int tcount_s;
  int tid = threadIdx.x, wid = tid >> 6;
  if ((int)blockIdx.x >= nblk1) {
    // ---- pairs ----
    int p = ((int)blockIdx.x - nblk1) * 256 + tid;
    if (p >= N_PAIRS) return;
    float tf = 2.0f * BATCH - 1.0f;
    float disc = tf * tf - 8.0f * (float)p;
    int ii = (int)((tf - sqrtf(disc)) * 0.5f);
    if (ii < 0) ii = 0;
    if (ii > BATCH - 2) ii = BATCH - 2;
    while (ii > 0 &&
           (long long)ii * (BATCH - 1) - (long long)ii * (ii - 1) / 2 > p) --ii;
    while ((long long)(ii + 1) * (BATCH - 1) - (long long)(ii + 1) * ii / 2 <= p) ++ii;
    long long S = (long long)ii * (BATCH - 1) - (long long)ii * (ii - 1) / 2;
    int jj = ii + 1 + (int)(p - S);
    outp[p] = (float)bn[ii];
    outp[N_PAIRS + p] = (float)bn[jj];
    return;
  }
  // ---- P1 ----
  int c0 = (int)blockIdx.x * CHUNK;
  int nloc = min(CHUNK, N_EDGES - c0);   // tail (2880) multiple of 4
  for (int t = tid; t < 4 * NB1; t += 256) ((int*)h)[t] = 0;
  __syncthreads();
  int iv[CHUNK / 256];
  const int4* e_i4 = (const int4*)(e_i + c0);
#pragma unroll
  for (int k = 0; k < CHUNK / 1024; ++k) {
    int q = tid + 256 * k;
    int ebase = 4 * q;
    if (ebase < nloc) {
      int4 r = e_i4[q];
      iv[4 * k + 0] = r.x; iv[4 * k + 1] = r.y;
      iv[4 * k + 2] = r.z; iv[4 * k + 3] = r.w;
      atomicAdd(&h[wid][r.x >> RPB_LOG], 1);
      atomicAdd(&h[wid][r.y >> RPB_LOG], 1);
      atomicAdd(&h[wid][r.z >> RPB_LOG], 1);
      atomicAdd(&h[wid][r.w >> RPB_LOG], 1);
    } else {
      iv[4 * k + 0] = iv[4 * k + 1] = iv[4 * k + 2] = iv[4 * k + 3] = -1;
    }
  }
  __syncthreads();
  // Wave 0: combine per-wave hists, exclusive scan (2 bins/lane), write
  // bstart + per-wave cursor starts back into h, reserve global runs.
  if (tid < 64) {
    int a0 = h[0][tid], a1 = h[1][tid], a2 = h[2][tid], a3 = h[3][tid];
    int a = a0 + a1 + a2 + a3;
    int b0 = 0, b1 = 0, b2 = 0, b3 = 0, b = 0;
    if (tid + 64 < NB1) {
      b0 = h[0][tid + 64]; b1 = h[1][tid + 64];
      b2 = h[2][tid + 64]; b3 = h[3][tid + 64];
      b = b0 + b1 + b2 + b3;
    }
    int inc0 = a;
#pragma unroll
    for (int d = 1; d < 64; d <<= 1) {
      int v = __shfl_up(inc0, d, 64);
      if (tid >= d) inc0 += v;
    }
    int t0 = __shfl(inc0, 63, 64);
    int inc1 = b;
#pragma unroll
    for (int d = 1; d < 64; d <<= 1) {
      int v = __shfl_up(inc1, d, 64);
      if (tid >= d) inc1 += v;
    }
    int tot = t0 + __shfl(inc1, 63, 64);
    int e0 = inc0 - a;
    bstart[tid] = e0;
    h[0][tid] = e0;
    h[1][tid] = e0 + a0;
    h[2][tid] = e0 + a0 + a1;
    h[3][tid] = e0 + a0 + a1 + a2;
    basec[tid] = a ? atomicAdd(&fill1[tid], a) : 0;
    if (tid + 64 < NB1) {
      int e1 = t0 + inc1 - b;
      bstart[tid + 64] = e1;
      h[0][tid + 64] = e1;
      h[1][tid + 64] = e1 + b0;
      h[2][tid + 64] = e1 + b0 + b1;
      h[3][tid + 64] = e1 + b0 + b1 + b2;
      basec[tid + 64] = b ? atomicAdd(&fill1[tid + 64], b) : 0;
    }
    if (tid == 0) tcount_s = tot;
  }
  __syncthreads();
  const int4* e_j4 = (const int4*)(e_j + c0);
  const int4* st4 = (const int4*)(st + c0);
#pragma unroll
  for (int k = 0; k < CHUNK / 1024; ++k) {
    int q = tid + 256 * k;
    int ebase = 4 * q;
    if (ebase < nloc) {
      int4 jj = e_j4[q];
      int4 ss = st4[q];
      int js[4] = {jj.x, jj.y, jj.z, jj.w};
      int s4[4] = {ss.x, ss.y, ss.z, ss.w};
#pragma unroll
      for (int c = 0; c < 4; ++c) {
        int i = iv[4 * k + c];
        unsigned e = (unsigned)(c0 + ebase + c);
        int b = i >> RPB_LOG;
        int pos = atomicAdd(&h[wid][b], 1);   // per-wave cursor
        lkey[pos] = ((u64)(unsigned)i << 38) | ((u64)(unsigned)js[c] << 24) |
                    ((u64)e << 1) | (u64)(unsigned)s4[c];
      }
    }
  }
  __syncthreads();
  int tcount = tcount_s;
  for (int t = tid; t < tcount; t += 256) {
    u64 kv = lkey[t];
    int b = (int)(kv >> (38 + RPB_LOG));
    stage[basec[b] + (t - bstart[b])] = kv;
  }
}

// P2 v5: fine partition into 4-row GROUPS (2500 cursors). Chunk window =
// exactly 64 groups (rowbase 128-aligned, rows < rowbase+256). Drain runs
// ~64 contiguous elements per group per chunk. Per-wave hist + cursors.
// Rowsort full-sorts each group, so arbitrary order in the group slot is ok.
__global__ void __launch_bounds__(256) k_part2(
    const u64* __restrict__ stage, int* __restrict__ fill8,
    u64* __restrict__ sk) {
  __shared__ u64 lkey[CHUNK];
  __shared__ int h[4][NGCHUNK];      // per-wave hist, then per-wave cursors
  __shared__ int bstart[NGCHUNK], baser8[NGCHUNK];
  __shared__ int rowbase_s;
  int tid = threadIdx.x, wid = tid >> 6;
  int c0 = (int)blockIdx.x * CHUNK;
  int nloc = min(CHUNK, N_EDGES - c0);
  ((int*)h)[tid] = 0;                 // 4*64 = 256 ints
  if (tid == 0)
    rowbase_s = ((int)(stage[c0] >> (38 + RPB_LOG))) << RPB_LOG;
  __syncthreads();
  int rowbase = rowbase_s;
  int grp0 = rowbase >> GRPLOG;
  u64 kv[CHUNK / 256];
#pragma unroll
  for (int k = 0; k < CHUNK / 256; ++k) {
    int q = tid + 256 * k;
    if (q < nloc) {
      kv[k] = stage[c0 + q];
      int g = ((int)(kv[k] >> 38) - rowbase) >> GRPLOG;   // 0..63
      atomicAdd(&h[wid][g], 1);
    }
  }
  __syncthreads();
  // Wave 0: each lane owns one group; scan + cursors + reservations.
  if (tid < 64) {
    int b = tid;
    int a0 = h[0][b], a1 = h[1][b], a2 = h[2][b], a3 = h[3][b];
    int a = a0 + a1 + a2 + a3;
    int inc = a;
#pragma unroll
    for (int d = 1; d < 64; d <<= 1) {
      int v = __shfl_up(inc, d, 64);
      if (tid >= d) inc += v;
    }
    int excl = inc - a;
    bstart[b] = excl;
    h[0][b] = excl;
    h[1][b] = excl + a0;
    h[2][b] = excl + a0 + a1;
    h[3][b] = excl + a0 + a1 + a2;
    baser8[b] = a ? atomicAdd(&fill8[grp0 + b], a) : 0;
  }
  __syncthreads();
#pragma unroll
  for (int k = 0; k < CHUNK / 256; ++k) {
    int q = tid + 256 * k;
    if (q < nloc) {
      int g = ((int)(kv[k] >> 38) - rowbase) >> GRPLOG;
      int pos = atomicAdd(&h[wid][g], 1);   // per-wave cursor
      lkey[pos] = kv[k];
    }
  }
  __syncthreads();
  for (int t = tid; t < nloc; t += 256) {
    u64 v = lkey[t];
    int g = ((int)(v >> 38) - rowbase) >> GRPLOG;
    sk[baser8[g] + (t - bstart[g])] = v;
  }
}

// Rowsort-4: one 4-row group (~2000 keys) per block (grid 2500). Full-key
// sort of the group = concatenated sorted rows (R11-proven structure; GRPLOG
// parameter change only). LDS ~24.4 KB -> ~6 blocks/CU (2x R11 residency).
// Bin d = (row-r0)<<7 | ((key38 - jbase<<24) >> sh_row), sh_row adaptive ->
// <=128 bins/row, ~4 keys/bin everywhere (idx bits split duplicate-j runs).
__global__ void __launch_bounds__(256) k_rowsort_key(
    const u64* __restrict__ sk, const int* __restrict__ off,
    const float* __restrict__ times, const unsigned* __restrict__ selbits,
    float* __restrict__ out) {
  __shared__ u64 buf[GCAP];
  __shared__ int hist[GBINS], cur[GBINS];
  __shared__ unsigned bits[320];
  __shared__ int wsum4[4];
  int tid = threadIdx.x, lane = tid & 63, wid = tid >> 6;
  int r0 = (int)blockIdx.x << GRPLOG;
  int o0 = off[r0], o1 = off[r0 + (1 << GRPLOG)];
  int blen = o1 - o0;
  if (blen <= 0) return;
  if (blen > GCAP) blen = GCAP;   // avg 2000, +6.8 sigma: unreachable
  // Issue key loads first (HBM latency overlaps LDS init).
  u64 kv[KPT];
  int dv[KPT], rv[KPT];
#pragma unroll
  for (int k = 0; k < KPT; ++k) {
    int t = tid + 256 * k;
    kv[k] = (t < blen) ? sk[o0 + t] : 0;
  }
  for (int t = tid; t < GBINS; t += 256) hist[t] = 0;
  for (int t = tid; t < NBITSW; t += 256) bits[t] = selbits[t];
  __syncthreads();   // B1
  // Bin + histogram.
#pragma unroll
  for (int k = 0; k < KPT; ++k) {
    int t = tid + 256 * k;
    if (t < blen) {
      u64 v = kv[k];
      int row = (int)(v >> 38);
      int span = N_NODES - 1 - row;                    // >= 1
      int sh = 17 + ((span > 1) ? (32 - __clz(span - 1)) : 0);
      u64 rel = (v & 0x3FFFFFFFFFull) - ((u64)(row + 1) << 24);
      int d = ((row - r0) << 7) | (int)(rel >> sh);    // inner < 128
      dv[k] = d;
      atomicAdd(&hist[d], 1);
    } else {
      dv[k] = -1;
    }
  }
  __syncthreads();   // B2
  // Block-wide exclusive scan of 512 bins (2 consecutive per thread).
  {
    int b2 = tid * 2;
    int c0 = hist[b2], c1 = hist[b2 + 1];
    int sum = c0 + c1;
    int inc = sum;
#pragma unroll
    for (int d = 1; d < 64; d <<= 1) {
      int v = __shfl_up(inc, d, 64);
      if (lane >= d) inc += v;
    }
    if (lane == 63) wsum4[wid] = inc;
    __syncthreads();   // B3
    int woff = 0;
    for (int w = 0; w < wid; ++w) woff += wsum4[w];
    int excl = woff + inc - sum;
    hist[b2] = excl;           cur[b2] = excl;
    hist[b2 + 1] = excl + c0;  cur[b2 + 1] = excl + c0;
  }
  __syncthreads();   // B4
  // Scatter into bins (order within bin arbitrary).
#pragma unroll
  for (int k = 0; k < KPT; ++k) {
    if (dv[k] >= 0) {
      int pos = atomicAdd(&cur[dv[k]], 1);
      buf[pos] = kv[k];
    }
  }
  __syncthreads();   // B5
  // Rank within bin [hist[d], cur[d]) by full key (unique).
#pragma unroll
  for (int k = 0; k < KPT; ++k) {
    if (dv[k] >= 0) {
      u64 me = kv[k];
      int s0 = hist[dv[k]];
      int s1 = cur[dv[k]];
      int r = 0;
      for (int q = s0; q < s1; ++q) r += (buf[q] < me) ? 1 : 0;
      rv[k] = s0 + r;
    }
  }
  __syncthreads();   // B6: rank reads done before in-place writeback
#pragma unroll
  for (int k = 0; k < KPT; ++k)
    if (dv[k] >= 0) buf[rv[k]] = kv[k];
  __syncthreads();   // B7
  // Coalesced emit (R11-proven pattern; row decoded from key).
  for (int t = tid; t < blen; t += 256) {
    u64 k = buf[t];
    int row = (int)(k >> 38);
    int j = (int)((k >> 24) & 0x3FFFull);
    int idx = (int)((k >> 1) & 0x7FFFFFull);
    int p = o0 + t;
    out[OUT_ES0 + p] = (float)row;
    out[OUT_ES1 + p] = (float)j;
    bool m = ((bits[row >> 5] >> (row & 31)) & 1u) &&
             ((bits[j >> 5] >> (j & 31)) & 1u);
    out[OUT_T + p] = m ? times[idx] : 0.0f;
    out[OUT_S + p] = m ? (float)(int)(k & 1ull) : 0.0f;
    out[OUT_M + p] = m ? 1.0f : 0.0f;
  }
}

// ---- Fallback path (ws too small for u64 keys): R4-style 4B idx scatter ----
__global__ void __launch_bounds__(256) k_scatter_idx(
    const int4* __restrict__ e_i4, int* __restrict__ fill,
    unsigned* __restrict__ sk) {
  int t = blockIdx.x * blockDim.x + threadIdx.x;
  if (t >= N_EDGES / 4) return;
  int4 r = e_i4[t];
  unsigned e = 4u * (unsigned)t;
  int c0 = atomicAdd(&fill[r.x], 1);
  int c1 = atomicAdd(&fill[r.y], 1);
  int c2 = atomicAdd(&fill[r.z], 1);
  int c3 = atomicAdd(&fill[r.w], 1);
  sk[c0] = e;
  sk[c1] = e + 1;
  sk[c2] = e + 2;
  sk[c3] = e + 3;
}

__global__ void __launch_bounds__(256) k_rowsort_idx(
    const unsigned* __restrict__ sk, const int* __restrict__ e_j_arr,
    const int* __restrict__ off, const float* __restrict__ times,
    const int* __restrict__ states, const int* __restrict__ sel,
    float* __restrict__ out) {
  __shared__ u64 key[2048];
  int row = blockIdx.x;
  int o0 = off[row], o1 = off[row + 1];
  int len = o1 - o0;
  if (len <= 0) return;
  if (len > 2048) len = 2048;
  int M = 2;
  while (M < len) M <<= 1;
  for (int t = threadIdx.x; t < M; t += blockDim.x) {
    if (t < len) {
      unsigned e = sk[o0 + t];
      key[t] = ((u64)(unsigned)e_j_arr[e] << 32) | e;
    } else {
      key[t] = 0xFFFFFFFFFFFFFFFFull;
    }
  }
  __syncthreads();
  for (int k = 2; k <= M; k <<= 1) {
    for (int j = k >> 1; j > 0; j >>= 1) {
      for (int t = threadIdx.x; t < M; t += blockDim.x) {
        int ixj = t ^ j;
        if (ixj > t) {
          u64 a = key[t], b = key[ixj];
          bool up = ((t & k) == 0);
          if (up ? (a > b) : (a < b)) {
            key[t] = b;
            key[ixj] = a;
          }
        }
      }
      __syncthreads();
    }
  }
  int mi = sel[row];
  float frow = (float)row;
  for (int t = threadIdx.x; t < len; t += blockDim.x) {
    u64 k = key[t];
    int j = (int)(k >> 32);
    int idx = (int)(k & 0xFFFFFFFFull);
    int p = o0 + t;
    out[OUT_ES0 + p] = frow;
    out[OUT_ES1 + p] = (float)j;
    bool m = (mi != 0) && (sel[j] != 0);
    float tm = 0.0f, sv = 0.0f;
    if (m) {
      tm = times[idx];
      sv = (float)states[idx];
    }
    out[OUT_T + p] = tm;
    out[OUT_S + p] = sv;
    out[OUT_M + p] = m ? 1.0f : 0.0f;
  }
}

extern "C" void kernel_launch(void* const* d_in, const int* in_sizes, int n_in,
                              void* d_out, int out_size, void* d_ws, size_t ws_size,
                              hipStream_t stream) {
  const int* edges = (const int*)d_in[0];       // (2, E): [0..E)=i, [E..2E)=j
  const float* times = (const float*)d_in[1];
  const int* states = (const int*)d_in[2];
  const int* e_i = edges;
  const int* e_j = edges + N_EDGES;
  float* out = (float*)d_out;
  char* ws = (char*)d_ws;

  int* fill1 = (int*)(ws + WS_KEYS);            // 79 ints
  int* fill8 = (int*)(ws + WS_KEYS + 4096);     // 2500 ints (same dead region)
  int* sel = (int*)(ws + WS_SEL);
  int* bn = (int*)(ws + WS_BN);
  int* cnt = (int*)(ws + WS_CNT);
  unsigned* selbits = (unsigned*)(ws + WS_CNT); // aliases cnt (dead after scan)
  int* fill = (int*)(ws + WS_FILL);
  int* rankc = (int*)(ws + WS_FILL);            // rankc aliases fill (phase-ordered)
  int* off = (int*)(ws + WS_OFF);
  u64* sk64 = (u64*)(ws + WS_SCRATCH);
  unsigned* sk32 = (unsigned*)(ws + WS_SCRATCH);
  // Staging buffer for P1 output: the es0/es1 output region (exactly 40 MB),
  // fully consumed by P2 before k_rowsort_key overwrites it.
  u64* stage = (u64*)(out + OUT_ES0);
  int use64 = (ws_size >= (size_t)WS_SCRATCH + 8ull * N_EDGES) ? 1 : 0;

  hipMemsetAsync(ws + WS_CNT, 0, 80000, stream);  // cnt + rankc (contiguous)

  int npair_b = (N_PAIRS + 255) / 256;
  k_rankhist<<<RANK_BLKS + HIST_BLKS, 256, 0, stream>>>(rankc, cnt,
                                                        (const int4*)e_i);
  k_scan_all<<<1, 1024, 0, stream>>>(rankc, sel, bn, out + OUT_BN, cnt, off,
                                     fill, fill1, fill8, selbits);
  if (use64) {
    int nblk1 = (N_EDGES + CHUNK - 1) / CHUNK;
    k_pairs_part1<<<nblk1 + npair_b, 256, 0, stream>>>(
        e_i, e_j, states, fill1, stage, bn, out + OUT_PAIRS0, nblk1);
    k_part2<<<nblk1, 256, 0, stream>>>(stage, fill8, sk64);
    k_rowsort_key<<<NGRP, 256, 0, stream>>>(sk64, off, times, selbits, out);
  } else {
    k_pairs_part1<<<npair_b, 256, 0, stream>>>(
        e_i, e_j, states, fill1, stage, bn, out + OUT_PAIRS0, 0);
    k_scatter_idx<<<(N_EDGES / 4 + 255) / 256, 256, 0, stream>>>(
        (const int4*)e_i, fill, sk32);
    k_rowsort_idx<<<N_NODES, 256, 0, stream>>>(sk32, e_j, off, times, states,
                                               sel, out);
  }
}